// Round 3
// baseline (1209.020 us; speedup 1.0000x reference)
//
#include <hip/hip_runtime.h>
#include <hip/hip_bf16.h>
#include <math.h>

#define NEG_SLOPE 0.2f

__device__ __forceinline__ float leaky(float x) { return x > 0.f ? x : NEG_SLOPE * x; }

// ---------------- CSR build ----------------
__global__ void hist_kernel(const int* __restrict__ dst, int* __restrict__ deg, int E) {
  int e = blockIdx.x * blockDim.x + threadIdx.x;
  if (e < E) atomicAdd(&deg[dst[e]], 1);
}

__global__ void scan1_kernel(const int* __restrict__ deg, int* __restrict__ exc,
                             int* __restrict__ bsum, int N) {
  __shared__ int sm[512];
  int t = threadIdx.x;
  int i = blockIdx.x * 512 + t;
  int v = (i < N) ? deg[i] : 0;
  sm[t] = v; __syncthreads();
  for (int o = 1; o < 512; o <<= 1) {
    int x = (t >= o) ? sm[t - o] : 0;
    __syncthreads();
    sm[t] += x;
    __syncthreads();
  }
  if (i < N) exc[i] = sm[t] - v;
  if (t == 511) bsum[blockIdx.x] = sm[511];
}

__global__ void scan2_kernel(const int* __restrict__ bsum, int* __restrict__ bbase, int nb) {
  __shared__ int sm[256];
  int t = threadIdx.x;
  int v = (t < nb) ? bsum[t] : 0;
  sm[t] = v; __syncthreads();
  for (int o = 1; o < 256; o <<= 1) {
    int x = (t >= o) ? sm[t - o] : 0;
    __syncthreads();
    sm[t] += x;
    __syncthreads();
  }
  if (t < nb) bbase[t] = sm[t] - v;
}

__global__ void scan3_kernel(const int* __restrict__ exc, const int* __restrict__ bbase,
                             int* __restrict__ off, int* __restrict__ cur, int N, int E) {
  int i = blockIdx.x * blockDim.x + threadIdx.x;
  if (i < N) {
    int v = exc[i] + bbase[i >> 9];
    off[i] = v;
    cur[i] = v;
  }
  if (i == 0) off[N] = E;
}

__global__ void scatter_kernel(const int* __restrict__ src, const int* __restrict__ dst,
                               int* __restrict__ cur, int* __restrict__ es, int E) {
  int e = blockIdx.x * blockDim.x + threadIdx.x;
  if (e < E) {
    int p = atomicAdd(&cur[dst[e]], 1);
    es[p] = src[e];
  }
}

// ---------------- fp32 tiled GEMM: C[M,N] = A[M,K] @ B[K,N] ----------------
// 128x128 tile, TM=TN=8: 64 FMA per 4 ds_read_b128 per k-step.
template <int BM, int BN, int BK, int TM, int TN>
__global__ __launch_bounds__(256) void gemm_kernel(const float* __restrict__ A,
                                                   const float* __restrict__ B,
                                                   float* __restrict__ C,
                                                   int M, int N, int K) {
  static_assert((BM / TM) * (BN / TN) == 256, "256 threads");
  static_assert(TN % 4 == 0 && TM % 4 == 0, "float4");
  constexpr int TCN = BN / TN;  // threads along N
  __shared__ float As[BK][BM + 4];  // transposed-A tile; +4 keeps 16B alignment
  __shared__ float Bs[BK][BN];
  int tid = threadIdx.x;
  int bm = blockIdx.x * BM;
  int bn = blockIdx.y * BN;
  int tr = tid / TCN, tc = tid % TCN;
  float acc[TM][TN] = {};

  constexpr int A_F4 = (BM * BK) / (256 * 4);
  constexpr int B_F4 = (BK * BN) / (256 * 4);
  constexpr int ACPR = BK / 4;   // float4 chunks per A row
  constexpr int BCPR = BN / 4;   // float4 chunks per B row

  for (int k0 = 0; k0 < K; k0 += BK) {
#pragma unroll
    for (int i = 0; i < A_F4; ++i) {
      int idx = tid + i * 256;
      int r = idx / ACPR;
      int c = (idx % ACPR) * 4;
      int row = bm + r;
      float4 v = make_float4(0.f, 0.f, 0.f, 0.f);
      if (row < M) v = *(const float4*)&A[(size_t)row * K + k0 + c];
      As[c + 0][r] = v.x;
      As[c + 1][r] = v.y;
      As[c + 2][r] = v.z;
      As[c + 3][r] = v.w;
    }
#pragma unroll
    for (int i = 0; i < B_F4; ++i) {
      int idx = tid + i * 256;
      int r = idx / BCPR;
      int c = (idx % BCPR) * 4;
      *(float4*)&Bs[r][c] = *(const float4*)&B[(size_t)(k0 + r) * N + bn + c];
    }
    __syncthreads();
#pragma unroll
    for (int k = 0; k < BK; ++k) {
      float a[TM], b[TN];
#pragma unroll
      for (int i = 0; i < TM; i += 4) *(float4*)&a[i] = *(const float4*)&As[k][tr * TM + i];
#pragma unroll
      for (int j = 0; j < TN; j += 4) *(float4*)&b[j] = *(const float4*)&Bs[k][tc * TN + j];
#pragma unroll
      for (int i = 0; i < TM; ++i)
#pragma unroll
        for (int j = 0; j < TN; ++j) acc[i][j] += a[i] * b[j];
    }
    __syncthreads();
  }
#pragma unroll
  for (int i = 0; i < TM; ++i) {
    int row = bm + tr * TM + i;
    if (row < M) {
#pragma unroll
      for (int j = 0; j < TN; j += 4) {
        float4 v = make_float4(acc[i][j], acc[i][j + 1], acc[i][j + 2], acc[i][j + 3]);
        *(float4*)&C[(size_t)row * N + bn + tc * TN + j] = v;
      }
    }
  }
}

// ---------------- attention dots: one wave per node, coalesced full-row read ----------------
template <int C>
__global__ __launch_bounds__(256) void adot_kernel(const float* __restrict__ h,
                                                   const float* __restrict__ att_src,
                                                   const float* __restrict__ att_dst,
                                                   float* __restrict__ a_src,
                                                   float* __restrict__ a_dst, int N) {
  int w = (blockIdx.x * 256 + threadIdx.x) >> 6;
  int lane = threadIdx.x & 63;
  if (w >= N) return;
  int head = lane >> 4;
  int l16 = lane & 15;
  float s, d;
  if constexpr (C == 32) {
    float2 hv = *(const float2*)&h[(size_t)w * 128 + lane * 2];
    float2 sv = *(const float2*)&att_src[head * 32 + l16 * 2];
    float2 dv = *(const float2*)&att_dst[head * 32 + l16 * 2];
    s = hv.x * sv.x + hv.y * sv.y;
    d = hv.x * dv.x + hv.y * dv.y;
  } else {
    float4 hv = *(const float4*)&h[(size_t)w * 256 + lane * 4];
    float4 sv = *(const float4*)&att_src[head * 64 + l16 * 4];
    float4 dv = *(const float4*)&att_dst[head * 64 + l16 * 4];
    s = hv.x * sv.x + hv.y * sv.y + hv.z * sv.z + hv.w * sv.w;
    d = hv.x * dv.x + hv.y * dv.y + hv.z * dv.z + hv.w * dv.w;
  }
#pragma unroll
  for (int o = 1; o < 16; o <<= 1) {
    s += __shfl_xor(s, o);
    d += __shfl_xor(d, o);
  }
  if (l16 == 0) {
    a_src[(size_t)w * 4 + head] = s;
    a_dst[(size_t)w * 4 + head] = d;
  }
}

// ---------------- layer-1 aggregation: single pass, unnormalized accumulate ----------------
// One wave per dst node. Each lane loops over ALL edges: w = exp(leaky(..)) for its head
// (uniform within each 16-lane head group), accumulates sum += w and acc += w*h_row.
// Denominator needs no shuffles: every lane saw every edge. Fused bias + ELU.
__global__ __launch_bounds__(256) void agg1_kernel(
    const float* __restrict__ h1, const float* __restrict__ asrc, const float* __restrict__ adst,
    const int* __restrict__ off, const int* __restrict__ es,
    const float* __restrict__ b1, float* __restrict__ x2, int N) {
  int n = (blockIdx.x * 256 + threadIdx.x) >> 6;
  int lane = threadIdx.x & 63;
  if (n >= N) return;
  int beg = off[n], end = off[n + 1];
  int myh = lane >> 4;
  float admy = adst[(size_t)n * 4 + myh];
  const float2* h1v = (const float2*)h1;
  float sum = 0.f;
  float2 acc = make_float2(0.f, 0.f);
  for (int j = beg; j < end; ++j) {
    int se = es[j];
    float w = __expf(leaky(asrc[(size_t)se * 4 + myh] + admy));
    sum += w;
    float2 hv = h1v[(size_t)se * 64 + lane];
    acc.x += w * hv.x;
    acc.y += w * hv.y;
  }
  float rs = 1.f / sum;
  int c = lane * 2;
  float2 bv = *(const float2*)&b1[c];
  float y0 = acc.x * rs + bv.x;
  float y1 = acc.y * rs + bv.y;
  y0 = y0 > 0.f ? y0 : expm1f(y0);  // ELU
  y1 = y1 > 0.f ? y1 : expm1f(y1);
  *(float2*)&x2[(size_t)n * 128 + c] = make_float2(y0, y1);
}

// ---------------- layer-2 aggregation: single pass + fused head-mean + bias ----------------
__global__ __launch_bounds__(256) void agg2_kernel(
    const float* __restrict__ h2, const float* __restrict__ asrc, const float* __restrict__ adst,
    const int* __restrict__ off, const int* __restrict__ es,
    const float* __restrict__ b2, float* __restrict__ out, int N) {
  int n = (blockIdx.x * 256 + threadIdx.x) >> 6;
  int lane = threadIdx.x & 63;
  if (n >= N) return;
  int beg = off[n], end = off[n + 1];
  int myh = lane >> 4;
  float admy = adst[(size_t)n * 4 + myh];
  const float4* h2v = (const float4*)h2;
  float sum = 0.f;
  float4 acc = make_float4(0.f, 0.f, 0.f, 0.f);
  for (int j = beg; j < end; ++j) {
    int se = es[j];
    float w = __expf(leaky(asrc[(size_t)se * 4 + myh] + admy));
    sum += w;
    float4 hv = h2v[(size_t)se * 64 + lane];
    acc.x += w * hv.x;
    acc.y += w * hv.y;
    acc.z += w * hv.z;
    acc.w += w * hv.w;
  }
  // normalize per head BEFORE cross-head reduce (denominators differ per head)
  float rs = 1.f / sum;
  acc.x *= rs; acc.y *= rs; acc.z *= rs; acc.w *= rs;
  // sum over the 4 heads (lanes differing in bits 4,5), then mean + bias
#pragma unroll
  for (int d = 16; d < 64; d <<= 1) {
    acc.x += __shfl_xor(acc.x, d);
    acc.y += __shfl_xor(acc.y, d);
    acc.z += __shfl_xor(acc.z, d);
    acc.w += __shfl_xor(acc.w, d);
  }
  if (lane < 16) {
    int c = lane * 4;
    float4 bv = *(const float4*)&b2[c];
    float4 o;
    o.x = acc.x * 0.25f + bv.x;
    o.y = acc.y * 0.25f + bv.y;
    o.z = acc.z * 0.25f + bv.z;
    o.w = acc.w * 0.25f + bv.w;
    *(float4*)&out[(size_t)n * 64 + c] = o;
  }
}

static inline int ceil_div(int a, int b) { return (a + b - 1) / b; }

extern "C" void kernel_launch(void* const* d_in, const int* in_sizes, int n_in,
                              void* d_out, int out_size, void* d_ws, size_t ws_size,
                              hipStream_t stream) {
  const float* x = (const float*)d_in[0];
  const int* src = (const int*)d_in[1];
  const int* dst = (const int*)d_in[2];
  const float* W1 = (const float*)d_in[3];
  const float* att_src1 = (const float*)d_in[4];
  const float* att_dst1 = (const float*)d_in[5];
  const float* b1 = (const float*)d_in[6];
  const float* W2 = (const float*)d_in[7];
  const float* att_src2 = (const float*)d_in[8];
  const float* att_dst2 = (const float*)d_in[9];
  const float* b2 = (const float*)d_in[10];
  float* out = (float*)d_out;

  const int N = in_sizes[0] / 512;  // 100000
  const int E = in_sizes[1];        // 1700000

  // -------- workspace layout (aliased where lifetimes are stream-disjoint) --------
  char* ws = (char*)d_ws;
  size_t o = 0;
  auto alloc = [&](size_t bytes) -> void* {
    o = (o + 255) & ~(size_t)255;
    void* p = ws + o;
    o += bytes;
    return p;
  };
  // region A: h2 (N*256 f32). h1 (N*128 f32) aliases its base — h1 is dead before
  // gemm2 writes h2 (gemm2 reads only x2/W2; stream-ordered).
  float* h2 = (float*)alloc((size_t)N * 256 * 4);
  float* h1 = h2;
  // region B: x2 (N*128 f32). CSR build temporaries alias it — all dead before
  // agg1 writes x2.
  float* x2 = (float*)alloc((size_t)N * 128 * 4);
  int* deg = (int*)x2;
  int* exc = deg + N;
  int* cur = exc + N;
  int* bsum = cur + N;      // 256 ints
  int* bbase = bsum + 256;  // 256 ints
  // persistent buffers
  float* as1 = (float*)alloc((size_t)N * 4 * 4);
  float* ad1 = (float*)alloc((size_t)N * 4 * 4);
  float* as2 = (float*)alloc((size_t)N * 4 * 4);
  float* ad2 = (float*)alloc((size_t)N * 4 * 4);
  int* off = (int*)alloc((size_t)(N + 1) * 4);
  int* es = (int*)alloc((size_t)E * 4);

  const int nb = ceil_div(N, 512);  // 196 (<=256 -> single scan2 block)

  // -------- CSR build (shared by both layers) --------
  hipMemsetAsync(deg, 0, (size_t)N * 4, stream);
  hist_kernel<<<ceil_div(E, 256), 256, 0, stream>>>(dst, deg, E);
  scan1_kernel<<<nb, 512, 0, stream>>>(deg, exc, bsum, N);
  scan2_kernel<<<1, 256, 0, stream>>>(bsum, bbase, nb);
  scan3_kernel<<<ceil_div(N, 256), 256, 0, stream>>>(exc, bbase, off, cur, N, E);
  scatter_kernel<<<ceil_div(E, 256), 256, 0, stream>>>(src, dst, cur, es, E);

  // -------- layer 1 --------
  gemm_kernel<128, 128, 16, 8, 8>
      <<<dim3(ceil_div(N, 128), 1), 256, 0, stream>>>(x, W1, h1, N, 128, 512);
  adot_kernel<32><<<ceil_div(N * 64, 256), 256, 0, stream>>>(h1, att_src1, att_dst1, as1, ad1, N);
  agg1_kernel<<<ceil_div(N, 4), 256, 0, stream>>>(h1, as1, ad1, off, es, b1, x2, N);

  // -------- layer 2 --------
  gemm_kernel<128, 128, 16, 8, 8>
      <<<dim3(ceil_div(N, 128), 2), 256, 0, stream>>>(x2, W2, h2, N, 256, 128);
  adot_kernel<64><<<ceil_div(N * 64, 256), 256, 0, stream>>>(h2, att_src2, att_dst2, as2, ad2, N);
  agg2_kernel<<<ceil_div(N, 4), 256, 0, stream>>>(h2, as2, ad2, off, es, b2, out, N);
}

// Round 4
// 1087.204 us; speedup vs baseline: 1.1120x; 1.1120x over previous
//
#include <hip/hip_runtime.h>
#include <hip/hip_bf16.h>
#include <math.h>

#define NEG_SLOPE 0.2f

using u16 = unsigned short;
typedef __attribute__((ext_vector_type(2))) u16 u16x2;
typedef __attribute__((ext_vector_type(4))) u16 u16x4;
typedef __attribute__((ext_vector_type(8))) short s16x8;
typedef __attribute__((ext_vector_type(4))) float f32x4;

__device__ __forceinline__ float leaky(float x) { return x > 0.f ? x : NEG_SLOPE * x; }

// bf16 split helpers (round-to-nearest-even on the hi part; lo captures the remainder)
__device__ __forceinline__ u16 bfhi(float f) {
  unsigned u = __float_as_uint(f);
  return (u16)((u + 0x7FFFu + ((u >> 16) & 1u)) >> 16);
}
__device__ __forceinline__ float bf2f(u16 h) { return __uint_as_float((unsigned)h << 16); }
__device__ __forceinline__ void bfsplit(float f, u16& h, u16& l) {
  h = bfhi(f);
  l = bfhi(f - bf2f(h));
}

// ---------------- CSR build ----------------
__global__ void hist_kernel(const int* __restrict__ dst, int* __restrict__ deg, int E) {
  int e = blockIdx.x * blockDim.x + threadIdx.x;
  if (e < E) atomicAdd(&deg[dst[e]], 1);
}

__global__ void scan1_kernel(const int* __restrict__ deg, int* __restrict__ exc,
                             int* __restrict__ bsum, int N) {
  __shared__ int sm[512];
  int t = threadIdx.x;
  int i = blockIdx.x * 512 + t;
  int v = (i < N) ? deg[i] : 0;
  sm[t] = v; __syncthreads();
  for (int o = 1; o < 512; o <<= 1) {
    int x = (t >= o) ? sm[t - o] : 0;
    __syncthreads();
    sm[t] += x;
    __syncthreads();
  }
  if (i < N) exc[i] = sm[t] - v;
  if (t == 511) bsum[blockIdx.x] = sm[511];
}

__global__ void scan2_kernel(const int* __restrict__ bsum, int* __restrict__ bbase, int nb) {
  __shared__ int sm[256];
  int t = threadIdx.x;
  int v = (t < nb) ? bsum[t] : 0;
  sm[t] = v; __syncthreads();
  for (int o = 1; o < 256; o <<= 1) {
    int x = (t >= o) ? sm[t - o] : 0;
    __syncthreads();
    sm[t] += x;
    __syncthreads();
  }
  if (t < nb) bbase[t] = sm[t] - v;
}

__global__ void scan3_kernel(const int* __restrict__ exc, const int* __restrict__ bbase,
                             int* __restrict__ off, int* __restrict__ cur, int N, int E) {
  int i = blockIdx.x * blockDim.x + threadIdx.x;
  if (i < N) {
    int v = exc[i] + bbase[i >> 9];
    off[i] = v;
    cur[i] = v;
  }
  if (i == 0) off[N] = E;
}

__global__ void scatter_kernel(const int* __restrict__ src, const int* __restrict__ dst,
                               int* __restrict__ cur, int* __restrict__ es, int E) {
  int e = blockIdx.x * blockDim.x + threadIdx.x;
  if (e < E) {
    int p = atomicAdd(&cur[dst[e]], 1);
    es[p] = src[e];
  }
}

// ---------------- W -> fragment-order bf16 hi/lo ----------------
// One wave per (ks, fn) sub-tile. Output: Bh/Bl[((ks*Nf + fn)*64 + lane)*8 + j]
// holds B[k = ks*32 + (lane>>4)*8 + j][n = fn*16 + (lane&15)].
__global__ void wconv_kernel(const float* __restrict__ W, u16* __restrict__ Bh,
                             u16* __restrict__ Bl, int K, int N) {
  int lane = threadIdx.x & 63;
  int blk = blockIdx.x;  // ks * (N/16) + fn
  int Nf = N >> 4;
  int ks = blk / Nf, fn = blk - ks * Nf;
  int col = fn * 16 + (lane & 15);
  int k0 = ks * 32 + (lane >> 4) * 8;
  u16 hh[8], ll[8];
#pragma unroll
  for (int j = 0; j < 8; ++j) {
    float f = W[(size_t)(k0 + j) * N + col];
    bfsplit(f, hh[j], ll[j]);
  }
  size_t o = ((size_t)blk * 64 + lane) * 8;
#pragma unroll
  for (int j = 0; j < 8; ++j) {
    Bh[o + j] = hh[j];
    Bl[o + j] = ll[j];
  }
}

// ---------------- MFMA GEMM with bf16 hi/lo error compensation ----------------
// C = A*B with A fp32 (CONVERT=true, split on the fly) or pre-split bf16 hi/lo
// (CONVERT=false). B pre-split in fragment order. Tile 128x128, BK=32,
// 4 waves (2x2), each wave 64x64 = 4x4 fragments of 16x16x32.
// 3-term compensation: Ah*Bh + Ah*Bl + Al*Bh (lo*lo term ~2^-16 rel, dropped).
template <bool CONVERT>
__global__ __launch_bounds__(256) void gemm_mfma(
    const float* __restrict__ Af, const u16* __restrict__ Ahg, const u16* __restrict__ Alg,
    const u16* __restrict__ Bhg, const u16* __restrict__ Blg,
    float* __restrict__ C, int M, int N, int K) {
  __shared__ u16 Ah[8 * 512];  // 8 sub-tiles x 64 lanes x 8 bf16 (fragment order)
  __shared__ u16 Al[8 * 512];
  int tid = threadIdx.x;
  int lane = tid & 63;
  int wid = tid >> 6;
  int wr = wid >> 1, wc = wid & 1;
  int bm = blockIdx.x * 128;
  int bn = blockIdx.y * 128;
  int Nf = N >> 4;
  f32x4 acc[4][4] = {};

  for (int ks = 0; ks < K; ks += 32) {
    __syncthreads();
    if constexpr (CONVERT) {
      // A tile 128 rows x 32 k fp32 -> hi/lo bf16 in fragment order.
      // chunk c: row = c>>3, kq = c&7 (float4 at k = kq*4)
#pragma unroll
      for (int i = 0; i < 4; ++i) {
        int c = tid + (i << 8);
        int row = c >> 3, kq = c & 7;
        float4 v = make_float4(0.f, 0.f, 0.f, 0.f);
        if (bm + row < M) v = *(const float4*)&Af[(size_t)(bm + row) * K + ks + kq * 4];
        u16 hx, lx, hy, ly, hz, lz, hw, lw;
        bfsplit(v.x, hx, lx); bfsplit(v.y, hy, ly);
        bfsplit(v.z, hz, lz); bfsplit(v.w, hw, lw);
        int off = (row >> 4) * 512 + ((row & 15) + ((kq >> 1) << 4)) * 8 + (kq & 1) * 4;
        u16x4 hv = {hx, hy, hz, hw};
        u16x4 lv = {lx, ly, lz, lw};
        *(u16x4*)&Ah[off] = hv;
        *(u16x4*)&Al[off] = lv;
      }
    } else {
      // A already bf16 hi/lo row-major; chunk c: row = c>>2, k8 = c&3 (8 bf16)
#pragma unroll
      for (int i = 0; i < 2; ++i) {
        int c = tid + (i << 8);
        int row = c >> 2, k8 = c & 3;
        size_t g = (size_t)(bm + row) * K + ks + k8 * 8;
        int off = (row >> 4) * 512 + ((row & 15) + (k8 << 4)) * 8;
        *(s16x8*)&Ah[off] = *(const s16x8*)&Ahg[g];
        *(s16x8*)&Al[off] = *(const s16x8*)&Alg[g];
      }
    }
    __syncthreads();

    s16x8 bh[4], bl[4];
    int ksi = ks >> 5;
#pragma unroll
    for (int fn = 0; fn < 4; ++fn) {
      int fnG = (bn >> 4) + wc * 4 + fn;
      size_t idx = (((size_t)ksi * Nf + fnG) * 64 + lane) * 8;
      bh[fn] = *(const s16x8*)&Bhg[idx];
      bl[fn] = *(const s16x8*)&Blg[idx];
    }
#pragma unroll
    for (int fm = 0; fm < 4; ++fm) {
      int st = wr * 4 + fm;
      s16x8 ah = *(const s16x8*)&Ah[st * 512 + lane * 8];
      s16x8 al = *(const s16x8*)&Al[st * 512 + lane * 8];
#pragma unroll
      for (int fn = 0; fn < 4; ++fn) {
        acc[fm][fn] = __builtin_amdgcn_mfma_f32_16x16x32_bf16(ah, bh[fn], acc[fm][fn], 0, 0, 0);
        acc[fm][fn] = __builtin_amdgcn_mfma_f32_16x16x32_bf16(ah, bl[fn], acc[fm][fn], 0, 0, 0);
        acc[fm][fn] = __builtin_amdgcn_mfma_f32_16x16x32_bf16(al, bh[fn], acc[fm][fn], 0, 0, 0);
      }
    }
  }
  // epilogue: C/D layout col = lane&15, row = (lane>>4)*4 + reg
#pragma unroll
  for (int fm = 0; fm < 4; ++fm) {
#pragma unroll
    for (int fn = 0; fn < 4; ++fn) {
#pragma unroll
      for (int r = 0; r < 4; ++r) {
        int row = bm + wr * 64 + fm * 16 + (lane >> 4) * 4 + r;
        int col = bn + wc * 64 + fn * 16 + (lane & 15);
        if (row < M) C[(size_t)row * N + col] = acc[fm][fn][r];
      }
    }
  }
}

// ---------------- attention dots: one wave per node, coalesced full-row read ----------------
template <int C>
__global__ __launch_bounds__(256) void adot_kernel(const float* __restrict__ h,
                                                   const float* __restrict__ att_src,
                                                   const float* __restrict__ att_dst,
                                                   float* __restrict__ a_src,
                                                   float* __restrict__ a_dst, int N) {
  int w = (blockIdx.x * 256 + threadIdx.x) >> 6;
  int lane = threadIdx.x & 63;
  if (w >= N) return;
  int head = lane >> 4;
  int l16 = lane & 15;
  float s, d;
  if constexpr (C == 32) {
    float2 hv = *(const float2*)&h[(size_t)w * 128 + lane * 2];
    float2 sv = *(const float2*)&att_src[head * 32 + l16 * 2];
    float2 dv = *(const float2*)&att_dst[head * 32 + l16 * 2];
    s = hv.x * sv.x + hv.y * sv.y;
    d = hv.x * dv.x + hv.y * dv.y;
  } else {
    float4 hv = *(const float4*)&h[(size_t)w * 256 + lane * 4];
    float4 sv = *(const float4*)&att_src[head * 64 + l16 * 4];
    float4 dv = *(const float4*)&att_dst[head * 64 + l16 * 4];
    s = hv.x * sv.x + hv.y * sv.y + hv.z * sv.z + hv.w * sv.w;
    d = hv.x * dv.x + hv.y * dv.y + hv.z * dv.z + hv.w * dv.w;
  }
#pragma unroll
  for (int o = 1; o < 16; o <<= 1) {
    s += __shfl_xor(s, o);
    d += __shfl_xor(d, o);
  }
  if (l16 == 0) {
    a_src[(size_t)w * 4 + head] = s;
    a_dst[(size_t)w * 4 + head] = d;
  }
}

// ---------------- layer-1 aggregation: single pass; writes x2 as bf16 hi/lo ----------------
__global__ __launch_bounds__(256) void agg1_kernel(
    const float* __restrict__ h1, const float* __restrict__ asrc, const float* __restrict__ adst,
    const int* __restrict__ off, const int* __restrict__ es,
    const float* __restrict__ b1, u16* __restrict__ x2h, u16* __restrict__ x2l, int N) {
  int n = (blockIdx.x * 256 + threadIdx.x) >> 6;
  int lane = threadIdx.x & 63;
  if (n >= N) return;
  int beg = off[n], end = off[n + 1];
  int myh = lane >> 4;
  float admy = adst[(size_t)n * 4 + myh];
  const float2* h1v = (const float2*)h1;
  float sum = 0.f;
  float2 acc = make_float2(0.f, 0.f);
  for (int j = beg; j < end; ++j) {
    int se = es[j];
    float w = __expf(leaky(asrc[(size_t)se * 4 + myh] + admy));
    sum += w;
    float2 hv = h1v[(size_t)se * 64 + lane];
    acc.x += w * hv.x;
    acc.y += w * hv.y;
  }
  float rs = 1.f / sum;
  int c = lane * 2;
  float2 bv = *(const float2*)&b1[c];
  float y0 = acc.x * rs + bv.x;
  float y1 = acc.y * rs + bv.y;
  y0 = y0 > 0.f ? y0 : expm1f(y0);  // ELU
  y1 = y1 > 0.f ? y1 : expm1f(y1);
  u16 h0, l0, h1b, l1b;
  bfsplit(y0, h0, l0);
  bfsplit(y1, h1b, l1b);
  u16x2 hw = {h0, h1b};
  u16x2 lw = {l0, l1b};
  *(u16x2*)&x2h[(size_t)n * 128 + c] = hw;
  *(u16x2*)&x2l[(size_t)n * 128 + c] = lw;
}

// ---------------- layer-2 aggregation: single pass + fused head-mean + bias ----------------
__global__ __launch_bounds__(256) void agg2_kernel(
    const float* __restrict__ h2, const float* __restrict__ asrc, const float* __restrict__ adst,
    const int* __restrict__ off, const int* __restrict__ es,
    const float* __restrict__ b2, float* __restrict__ out, int N) {
  int n = (blockIdx.x * 256 + threadIdx.x) >> 6;
  int lane = threadIdx.x & 63;
  if (n >= N) return;
  int beg = off[n], end = off[n + 1];
  int myh = lane >> 4;
  float admy = adst[(size_t)n * 4 + myh];
  const float4* h2v = (const float4*)h2;
  float sum = 0.f;
  float4 acc = make_float4(0.f, 0.f, 0.f, 0.f);
  for (int j = beg; j < end; ++j) {
    int se = es[j];
    float w = __expf(leaky(asrc[(size_t)se * 4 + myh] + admy));
    sum += w;
    float4 hv = h2v[(size_t)se * 64 + lane];
    acc.x += w * hv.x;
    acc.y += w * hv.y;
    acc.z += w * hv.z;
    acc.w += w * hv.w;
  }
  float rs = 1.f / sum;
  acc.x *= rs; acc.y *= rs; acc.z *= rs; acc.w *= rs;
#pragma unroll
  for (int d = 16; d < 64; d <<= 1) {
    acc.x += __shfl_xor(acc.x, d);
    acc.y += __shfl_xor(acc.y, d);
    acc.z += __shfl_xor(acc.z, d);
    acc.w += __shfl_xor(acc.w, d);
  }
  if (lane < 16) {
    int c = lane * 4;
    float4 bv = *(const float4*)&b2[c];
    float4 o;
    o.x = acc.x * 0.25f + bv.x;
    o.y = acc.y * 0.25f + bv.y;
    o.z = acc.z * 0.25f + bv.z;
    o.w = acc.w * 0.25f + bv.w;
    *(float4*)&out[(size_t)n * 64 + c] = o;
  }
}

static inline int ceil_div(int a, int b) { return (a + b - 1) / b; }

extern "C" void kernel_launch(void* const* d_in, const int* in_sizes, int n_in,
                              void* d_out, int out_size, void* d_ws, size_t ws_size,
                              hipStream_t stream) {
  const float* x = (const float*)d_in[0];
  const int* src = (const int*)d_in[1];
  const int* dst = (const int*)d_in[2];
  const float* W1 = (const float*)d_in[3];
  const float* att_src1 = (const float*)d_in[4];
  const float* att_dst1 = (const float*)d_in[5];
  const float* b1 = (const float*)d_in[6];
  const float* W2 = (const float*)d_in[7];
  const float* att_src2 = (const float*)d_in[8];
  const float* att_dst2 = (const float*)d_in[9];
  const float* b2 = (const float*)d_in[10];
  float* out = (float*)d_out;

  const int N = in_sizes[0] / 512;  // 100000 nodes (= GEMM M)
  const int E = in_sizes[1];        // 1700000 edges
  const int MP = ceil_div(N, 128) * 128;  // padded rows for 128-tall tiles

  // -------- workspace layout (aliased where lifetimes are stream-disjoint) --------
  char* ws = (char*)d_ws;
  size_t o = 0;
  auto alloc = [&](size_t bytes) -> void* {
    o = (o + 255) & ~(size_t)255;
    void* p = ws + o;
    o += bytes;
    return p;
  };
  // region A: h2 (N*256 f32). h1 (N*128 f32) aliases its base — h1 dead before gemm2 writes h2.
  float* h2 = (float*)alloc((size_t)N * 256 * 4);
  float* h1 = h2;
  // region B: x2h (MP*128 bf16). CSR temporaries alias it — dead before agg1 writes x2h.
  u16* x2h = (u16*)alloc((size_t)MP * 128 * 2);
  int* deg = (int*)x2h;
  int* exc = deg + N;
  int* cur = exc + N;
  int* bsum = cur + N;      // 256 ints
  int* bbase = bsum + 256;  // 256 ints
  u16* x2l = (u16*)alloc((size_t)MP * 128 * 2);
  // persistent buffers
  float* as1 = (float*)alloc((size_t)N * 4 * 4);
  float* ad1 = (float*)alloc((size_t)N * 4 * 4);
  float* as2 = (float*)alloc((size_t)N * 4 * 4);
  float* ad2 = (float*)alloc((size_t)N * 4 * 4);
  int* off = (int*)alloc((size_t)(N + 1) * 4);
  int* es = (int*)alloc((size_t)E * 4);
  // fragment-order bf16 hi/lo weight panels
  u16* Bh1 = (u16*)alloc((size_t)512 * 128 * 2);
  u16* Bl1 = (u16*)alloc((size_t)512 * 128 * 2);
  u16* Bh2 = (u16*)alloc((size_t)128 * 256 * 2);
  u16* Bl2 = (u16*)alloc((size_t)128 * 256 * 2);

  const int nb = ceil_div(N, 512);  // 196 (<=256 -> single scan2 block)

  // -------- weight conversion (tiny) --------
  wconv_kernel<<<(512 / 32) * (128 / 16), 64, 0, stream>>>(W1, Bh1, Bl1, 512, 128);
  wconv_kernel<<<(128 / 32) * (256 / 16), 64, 0, stream>>>(W2, Bh2, Bl2, 128, 256);

  // -------- CSR build (shared by both layers) --------
  hipMemsetAsync(deg, 0, (size_t)N * 4, stream);
  hist_kernel<<<ceil_div(E, 256), 256, 0, stream>>>(dst, deg, E);
  scan1_kernel<<<nb, 512, 0, stream>>>(deg, exc, bsum, N);
  scan2_kernel<<<1, 256, 0, stream>>>(bsum, bbase, nb);
  scan3_kernel<<<ceil_div(N, 256), 256, 0, stream>>>(exc, bbase, off, cur, N, E);
  scatter_kernel<<<ceil_div(E, 256), 256, 0, stream>>>(src, dst, cur, es, E);

  // -------- layer 1 --------
  gemm_mfma<true><<<dim3(MP / 128, 1), 256, 0, stream>>>(
      x, nullptr, nullptr, Bh1, Bl1, h1, N, 128, 512);
  adot_kernel<32><<<ceil_div(N * 64, 256), 256, 0, stream>>>(h1, att_src1, att_dst1, as1, ad1, N);
  agg1_kernel<<<ceil_div(N, 4), 256, 0, stream>>>(h1, as1, ad1, off, es, b1, x2h, x2l, N);

  // -------- layer 2 --------
  gemm_mfma<false><<<dim3(MP / 128, 2), 256, 0, stream>>>(
      nullptr, x2h, x2l, Bh2, Bl2, h2, N, 256, 128);
  adot_kernel<64><<<ceil_div(N * 64, 256), 256, 0, stream>>>(h2, att_src2, att_dst2, as2, ad2, N);
  agg2_kernel<<<ceil_div(N, 4), 256, 0, stream>>>(h2, as2, ad2, off, es, b2, out, N);
}

// Round 6
// 1042.260 us; speedup vs baseline: 1.1600x; 1.0431x over previous
//
#include <hip/hip_runtime.h>
#include <hip/hip_bf16.h>
#include <math.h>

#define NEG_SLOPE 0.2f

using u16 = unsigned short;
typedef __attribute__((ext_vector_type(2))) u16 u16x2;
typedef __attribute__((ext_vector_type(4))) u16 u16x4;
typedef __attribute__((ext_vector_type(8))) short s16x8;
typedef __attribute__((ext_vector_type(4))) float f32x4;

__device__ __forceinline__ float leaky(float x) { return x > 0.f ? x : NEG_SLOPE * x; }

// bf16 split helpers (round-to-nearest-even on the hi part; lo captures the remainder)
__device__ __forceinline__ u16 bfhi(float f) {
  unsigned u = __float_as_uint(f);
  return (u16)((u + 0x7FFFu + ((u >> 16) & 1u)) >> 16);
}
__device__ __forceinline__ float bf2f(u16 h) { return __uint_as_float((unsigned)h << 16); }
__device__ __forceinline__ void bfsplit(float f, u16& h, u16& l) {
  h = bfhi(f);
  l = bfhi(f - bf2f(h));
}

// ---------------- CSR build ----------------
__global__ void hist_kernel(const int* __restrict__ dst, int* __restrict__ deg, int E) {
  int e = blockIdx.x * blockDim.x + threadIdx.x;
  if (e < E) atomicAdd(&deg[dst[e]], 1);
}

__global__ void scan1_kernel(const int* __restrict__ deg, int* __restrict__ exc,
                             int* __restrict__ bsum, int N) {
  __shared__ int sm[512];
  int t = threadIdx.x;
  int i = blockIdx.x * 512 + t;
  int v = (i < N) ? deg[i] : 0;
  sm[t] = v; __syncthreads();
  for (int o = 1; o < 512; o <<= 1) {
    int x = (t >= o) ? sm[t - o] : 0;
    __syncthreads();
    sm[t] += x;
    __syncthreads();
  }
  if (i < N) exc[i] = sm[t] - v;
  if (t == 511) bsum[blockIdx.x] = sm[511];
}

__global__ void scan2_kernel(const int* __restrict__ bsum, int* __restrict__ bbase, int nb) {
  __shared__ int sm[256];
  int t = threadIdx.x;
  int v = (t < nb) ? bsum[t] : 0;
  sm[t] = v; __syncthreads();
  for (int o = 1; o < 256; o <<= 1) {
    int x = (t >= o) ? sm[t - o] : 0;
    __syncthreads();
    sm[t] += x;
    __syncthreads();
  }
  if (t < nb) bbase[t] = sm[t] - v;
}

__global__ void scan3_kernel(const int* __restrict__ exc, const int* __restrict__ bbase,
                             int* __restrict__ off, int* __restrict__ cur, int N, int E) {
  int i = blockIdx.x * blockDim.x + threadIdx.x;
  if (i < N) {
    int v = exc[i] + bbase[i >> 9];
    off[i] = v;
    cur[i] = v;
  }
  if (i == 0) off[N] = E;
}

__global__ void scatter_kernel(const int* __restrict__ src, const int* __restrict__ dst,
                               int* __restrict__ cur, int* __restrict__ es, int E) {
  int e = blockIdx.x * blockDim.x + threadIdx.x;
  if (e < E) {
    int p = atomicAdd(&cur[dst[e]], 1);
    es[p] = src[e];
  }
}

// ---------------- W -> fragment-order bf16 hi/lo ----------------
__global__ void wconv_kernel(const float* __restrict__ W, u16* __restrict__ Bh,
                             u16* __restrict__ Bl, int K, int N) {
  int lane = threadIdx.x & 63;
  int blk = blockIdx.x;  // ks * (N/16) + fn
  int Nf = N >> 4;
  int ks = blk / Nf, fn = blk - ks * Nf;
  int col = fn * 16 + (lane & 15);
  int k0 = ks * 32 + (lane >> 4) * 8;
  u16 hh[8], ll[8];
#pragma unroll
  for (int j = 0; j < 8; ++j) {
    float f = W[(size_t)(k0 + j) * N + col];
    bfsplit(f, hh[j], ll[j]);
  }
  size_t o = ((size_t)blk * 64 + lane) * 8;
#pragma unroll
  for (int j = 0; j < 8; ++j) {
    Bh[o + j] = hh[j];
    Bl[o + j] = ll[j];
  }
}

// ---------------- MFMA GEMM with bf16 hi/lo error compensation (R4-proven) ----------------
template <bool CONVERT>
__global__ __launch_bounds__(256) void gemm_mfma(
    const float* __restrict__ Af, const u16* __restrict__ Ahg, const u16* __restrict__ Alg,
    const u16* __restrict__ Bhg, const u16* __restrict__ Blg,
    float* __restrict__ C, int M, int N, int K) {
  __shared__ u16 Ah[8 * 512];  // 8 sub-tiles x 64 lanes x 8 bf16 (fragment order)
  __shared__ u16 Al[8 * 512];
  int tid = threadIdx.x;
  int lane = tid & 63;
  int wid = tid >> 6;
  int wr = wid >> 1, wc = wid & 1;
  int bm = blockIdx.x * 128;
  int bn = blockIdx.y * 128;
  int Nf = N >> 4;
  f32x4 acc[4][4] = {};

  for (int ks = 0; ks < K; ks += 32) {
    __syncthreads();
    if constexpr (CONVERT) {
#pragma unroll
      for (int i = 0; i < 4; ++i) {
        int c = tid + (i << 8);
        int row = c >> 3, kq = c & 7;
        float4 v = make_float4(0.f, 0.f, 0.f, 0.f);
        if (bm + row < M) v = *(const float4*)&Af[(size_t)(bm + row) * K + ks + kq * 4];
        u16 hx, lx, hy, ly, hz, lz, hw, lw;
        bfsplit(v.x, hx, lx); bfsplit(v.y, hy, ly);
        bfsplit(v.z, hz, lz); bfsplit(v.w, hw, lw);
        int off = (row >> 4) * 512 + ((row & 15) + ((kq >> 1) << 4)) * 8 + (kq & 1) * 4;
        u16x4 hv = {hx, hy, hz, hw};
        u16x4 lv = {lx, ly, lz, lw};
        *(u16x4*)&Ah[off] = hv;
        *(u16x4*)&Al[off] = lv;
      }
    } else {
#pragma unroll
      for (int i = 0; i < 2; ++i) {
        int c = tid + (i << 8);
        int row = c >> 2, k8 = c & 3;
        size_t g = (size_t)(bm + row) * K + ks + k8 * 8;
        int off = (row >> 4) * 512 + ((row & 15) + (k8 << 4)) * 8;
        *(s16x8*)&Ah[off] = *(const s16x8*)&Ahg[g];
        *(s16x8*)&Al[off] = *(const s16x8*)&Alg[g];
      }
    }
    __syncthreads();

    s16x8 bh[4], bl[4];
    int ksi = ks >> 5;
#pragma unroll
    for (int fn = 0; fn < 4; ++fn) {
      int fnG = (bn >> 4) + wc * 4 + fn;
      size_t idx = (((size_t)ksi * Nf + fnG) * 64 + lane) * 8;
      bh[fn] = *(const s16x8*)&Bhg[idx];
      bl[fn] = *(const s16x8*)&Blg[idx];
    }
#pragma unroll
    for (int fm = 0; fm < 4; ++fm) {
      int st = wr * 4 + fm;
      s16x8 ah = *(const s16x8*)&Ah[st * 512 + lane * 8];
      s16x8 al = *(const s16x8*)&Al[st * 512 + lane * 8];
#pragma unroll
      for (int fn = 0; fn < 4; ++fn) {
        acc[fm][fn] = __builtin_amdgcn_mfma_f32_16x16x32_bf16(ah, bh[fn], acc[fm][fn], 0, 0, 0);
        acc[fm][fn] = __builtin_amdgcn_mfma_f32_16x16x32_bf16(ah, bl[fn], acc[fm][fn], 0, 0, 0);
        acc[fm][fn] = __builtin_amdgcn_mfma_f32_16x16x32_bf16(al, bh[fn], acc[fm][fn], 0, 0, 0);
      }
    }
  }
  // epilogue: C/D layout col = lane&15, row = (lane>>4)*4 + reg
#pragma unroll
  for (int fm = 0; fm < 4; ++fm) {
#pragma unroll
    for (int fn = 0; fn < 4; ++fn) {
#pragma unroll
      for (int r = 0; r < 4; ++r) {
        int row = bm + wr * 64 + fm * 16 + (lane >> 4) * 4 + r;
        int col = bn + wc * 64 + fn * 16 + (lane & 15);
        if (row < M) C[(size_t)row * N + col] = acc[fm][fn][r];
      }
    }
  }
}

// ---------------- attention dots: one wave per node, coalesced full-row read ----------------
template <int C>
__global__ __launch_bounds__(256) void adot_kernel(const float* __restrict__ h,
                                                   const float* __restrict__ att_src,
                                                   const float* __restrict__ att_dst,
                                                   float* __restrict__ a_src,
                                                   float* __restrict__ a_dst, int N) {
  int w = (blockIdx.x * 256 + threadIdx.x) >> 6;
  int lane = threadIdx.x & 63;
  if (w >= N) return;
  int head = lane >> 4;
  int l16 = lane & 15;
  float s, d;
  if constexpr (C == 32) {
    float2 hv = *(const float2*)&h[(size_t)w * 128 + lane * 2];
    float2 sv = *(const float2*)&att_src[head * 32 + l16 * 2];
    float2 dv = *(const float2*)&att_dst[head * 32 + l16 * 2];
    s = hv.x * sv.x + hv.y * sv.y;
    d = hv.x * dv.x + hv.y * dv.y;
  } else {
    float4 hv = *(const float4*)&h[(size_t)w * 256 + lane * 4];
    float4 sv = *(const float4*)&att_src[head * 64 + l16 * 4];
    float4 dv = *(const float4*)&att_dst[head * 64 + l16 * 4];
    s = hv.x * sv.x + hv.y * sv.y + hv.z * sv.z + hv.w * sv.w;
    d = hv.x * dv.x + hv.y * dv.y + hv.z * dv.z + hv.w * dv.w;
  }
#pragma unroll
  for (int o = 1; o < 16; o <<= 1) {
    s += __shfl_xor(s, o);
    d += __shfl_xor(d, o);
  }
  if (l16 == 0) {
    a_src[(size_t)w * 4 + head] = s;
    a_dst[(size_t)w * 4 + head] = d;
  }
}

// ---------------- h2 fp32 -> bf16 compact copy ----------------
__global__ __launch_bounds__(256) void h2c_kernel(const float* __restrict__ h2,
                                                  u16* __restrict__ h2c, long total4) {
  long g = (long)blockIdx.x * 256 + threadIdx.x;
  if (g >= total4) return;
  float4 v = *(const float4*)&h2[g * 4];
  u16x4 o = {bfhi(v.x), bfhi(v.y), bfhi(v.z), bfhi(v.w)};
  *(u16x4*)&h2c[g * 4] = o;
}

// ---------------- layer-1 aggregation: single pass; writes x2 as bf16 hi/lo ----------------
__global__ __launch_bounds__(256) void agg1_kernel(
    const float* __restrict__ h1, const float* __restrict__ asrc, const float* __restrict__ adst,
    const int* __restrict__ off, const int* __restrict__ es,
    const float* __restrict__ b1, u16* __restrict__ x2h, u16* __restrict__ x2l, int N) {
  int n = (blockIdx.x * 256 + threadIdx.x) >> 6;
  int lane = threadIdx.x & 63;
  if (n >= N) return;
  int beg = off[n], end = off[n + 1];
  int myh = lane >> 4;
  float admy = adst[(size_t)n * 4 + myh];
  const float2* h1v = (const float2*)h1;
  float sum = 0.f;
  float2 acc = make_float2(0.f, 0.f);
  for (int j = beg; j < end; ++j) {
    int se = es[j];
    float w = __expf(leaky(asrc[(size_t)se * 4 + myh] + admy));
    sum += w;
    float2 hv = h1v[(size_t)se * 64 + lane];
    acc.x += w * hv.x;
    acc.y += w * hv.y;
  }
  float rs = 1.f / sum;
  int c = lane * 2;
  float2 bv = *(const float2*)&b1[c];
  float y0 = acc.x * rs + bv.x;
  float y1 = acc.y * rs + bv.y;
  y0 = y0 > 0.f ? y0 : expm1f(y0);  // ELU
  y1 = y1 > 0.f ? y1 : expm1f(y1);
  u16 h0, l0, h1b, l1b;
  bfsplit(y0, h0, l0);
  bfsplit(y1, h1b, l1b);
  u16x2 hw = {h0, h1b};
  u16x2 lw = {l0, l1b};
  *(u16x2*)&x2h[(size_t)n * 128 + c] = hw;
  *(u16x2*)&x2l[(size_t)n * 128 + c] = lw;
}

// ---------------- layer-2 aggregation: bf16 gather + fused head-mean + bias ----------------
__global__ __launch_bounds__(256) void agg2_kernel(
    const u16* __restrict__ h2c, const float* __restrict__ asrc, const float* __restrict__ adst,
    const int* __restrict__ off, const int* __restrict__ es,
    const float* __restrict__ b2, float* __restrict__ out, int N) {
  int n = (blockIdx.x * 256 + threadIdx.x) >> 6;
  int lane = threadIdx.x & 63;
  if (n >= N) return;
  int beg = off[n], end = off[n + 1];
  int myh = lane >> 4;
  float admy = adst[(size_t)n * 4 + myh];
  float sum = 0.f;
  float4 acc = make_float4(0.f, 0.f, 0.f, 0.f);
  for (int j = beg; j < end; ++j) {
    int se = es[j];
    float w = __expf(leaky(asrc[(size_t)se * 4 + myh] + admy));
    sum += w;
    u16x4 hv = *(const u16x4*)&h2c[(size_t)se * 256 + lane * 4];
    acc.x += w * bf2f(hv.x);
    acc.y += w * bf2f(hv.y);
    acc.z += w * bf2f(hv.z);
    acc.w += w * bf2f(hv.w);
  }
  float rs = 1.f / sum;
  acc.x *= rs; acc.y *= rs; acc.z *= rs; acc.w *= rs;
#pragma unroll
  for (int d = 16; d < 64; d <<= 1) {
    acc.x += __shfl_xor(acc.x, d);
    acc.y += __shfl_xor(acc.y, d);
    acc.z += __shfl_xor(acc.z, d);
    acc.w += __shfl_xor(acc.w, d);
  }
  if (lane < 16) {
    int c = lane * 4;
    float4 bv = *(const float4*)&b2[c];
    float4 o;
    o.x = acc.x * 0.25f + bv.x;
    o.y = acc.y * 0.25f + bv.y;
    o.z = acc.z * 0.25f + bv.z;
    o.w = acc.w * 0.25f + bv.w;
    *(float4*)&out[(size_t)n * 64 + c] = o;
  }
}

static inline int ceil_div(int a, int b) { return (a + b - 1) / b; }

extern "C" void kernel_launch(void* const* d_in, const int* in_sizes, int n_in,
                              void* d_out, int out_size, void* d_ws, size_t ws_size,
                              hipStream_t stream) {
  const float* x = (const float*)d_in[0];
  const int* src = (const int*)d_in[1];
  const int* dst = (const int*)d_in[2];
  const float* W1 = (const float*)d_in[3];
  const float* att_src1 = (const float*)d_in[4];
  const float* att_dst1 = (const float*)d_in[5];
  const float* b1 = (const float*)d_in[6];
  const float* W2 = (const float*)d_in[7];
  const float* att_src2 = (const float*)d_in[8];
  const float* att_dst2 = (const float*)d_in[9];
  const float* b2 = (const float*)d_in[10];
  float* out = (float*)d_out;

  const int N = in_sizes[0] / 512;        // 100000 nodes
  const int E = in_sizes[1];              // 1700000 edges
  const int MP = ceil_div(N, 128) * 128;  // padded rows for 128-tall tiles

  // -------- workspace layout (R4-proven) --------
  char* ws = (char*)d_ws;
  size_t o = 0;
  auto alloc = [&](size_t bytes) -> void* {
    o = (o + 255) & ~(size_t)255;
    void* p = ws + o;
    o += bytes;
    return p;
  };
  // region A: h2 fp32 (N*256). h1 (N*128 f32) aliases its base — h1 dead before gemm2 writes h2.
  float* h2 = (float*)alloc((size_t)N * 256 * 4);
  float* h1 = h2;
  // region B: x2h (MP*128 bf16) + x2l (MP*128 bf16), contiguous. CSR temporaries alias
  // x2h head (dead before agg1 writes x2h). h2c bf16 (N*256) aliases x2h+x2l — both
  // dead after gemm2 reads them; h2c written after gemm2, read by agg2.
  u16* x2h = (u16*)alloc((size_t)MP * 128 * 2);
  u16* x2l = (u16*)alloc((size_t)MP * 128 * 2);
  u16* h2c = x2h;  // spans x2h..x2l (51.20 MB <= 51.25 MB)
  int* deg = (int*)x2h;
  int* exc = deg + N;
  int* cur = exc + N;
  int* bsum = cur + N;      // 256 ints
  int* bbase = bsum + 256;  // 256 ints
  // persistent buffers
  float* as1 = (float*)alloc((size_t)N * 4 * 4);
  float* ad1 = (float*)alloc((size_t)N * 4 * 4);
  float* as2 = (float*)alloc((size_t)N * 4 * 4);
  float* ad2 = (float*)alloc((size_t)N * 4 * 4);
  int* off = (int*)alloc((size_t)(N + 1) * 4);
  int* es = (int*)alloc((size_t)E * 4);
  // fragment-order bf16 hi/lo weight panels
  u16* Bh1 = (u16*)alloc((size_t)512 * 128 * 2);
  u16* Bl1 = (u16*)alloc((size_t)512 * 128 * 2);
  u16* Bh2 = (u16*)alloc((size_t)128 * 256 * 2);
  u16* Bl2 = (u16*)alloc((size_t)128 * 256 * 2);

  const int nb = ceil_div(N, 512);  // 196 (<=256 -> single scan2 block)

  // -------- weight conversion (tiny) --------
  wconv_kernel<<<(512 / 32) * (128 / 16), 64, 0, stream>>>(W1, Bh1, Bl1, 512, 128);
  wconv_kernel<<<(128 / 32) * (256 / 16), 64, 0, stream>>>(W2, Bh2, Bl2, 128, 256);

  // -------- zero x2 padding rows (rows N..MP-1 read unguarded by gemm2's A-load) --------
  hipMemsetAsync(x2h + (size_t)N * 128, 0, (size_t)(MP - N) * 128 * 2, stream);
  hipMemsetAsync(x2l + (size_t)N * 128, 0, (size_t)(MP - N) * 128 * 2, stream);

  // -------- CSR build (shared by both layers) --------
  hipMemsetAsync(deg, 0, (size_t)N * 4, stream);
  hist_kernel<<<ceil_div(E, 256), 256, 0, stream>>>(dst, deg, E);
  scan1_kernel<<<nb, 512, 0, stream>>>(deg, exc, bsum, N);
  scan2_kernel<<<1, 256, 0, stream>>>(bsum, bbase, nb);
  scan3_kernel<<<ceil_div(N, 256), 256, 0, stream>>>(exc, bbase, off, cur, N, E);
  scatter_kernel<<<ceil_div(E, 256), 256, 0, stream>>>(src, dst, cur, es, E);

  // -------- layer 1 --------
  gemm_mfma<true><<<dim3(MP / 128, 1), 256, 0, stream>>>(
      x, nullptr, nullptr, Bh1, Bl1, h1, N, 128, 512);
  adot_kernel<32><<<ceil_div(N * 64, 256), 256, 0, stream>>>(h1, att_src1, att_dst1, as1, ad1, N);
  agg1_kernel<<<ceil_div(N, 4), 256, 0, stream>>>(h1, as1, ad1, off, es, b1, x2h, x2l, N);

  // -------- layer 2 --------
  gemm_mfma<false><<<dim3(MP / 128, 2), 256, 0, stream>>>(
      nullptr, x2h, x2l, Bh2, Bl2, h2, N, 256, 128);
  adot_kernel<64><<<ceil_div(N * 64, 256), 256, 0, stream>>>(h2, att_src2, att_dst2, as2, ad2, N);
  h2c_kernel<<<ceil_div(N * 64, 256), 256, 0, stream>>>(h2, h2c, (long)N * 64);
  agg2_kernel<<<ceil_div(N, 4), 256, 0, stream>>>(h2c, as2, ad2, off, es, b2, out, N);
}

// Round 7
// 1034.630 us; speedup vs baseline: 1.1686x; 1.0074x over previous
//
#include <hip/hip_runtime.h>
#include <hip/hip_bf16.h>
#include <math.h>

#define NEG_SLOPE 0.2f

using u16 = unsigned short;
typedef __attribute__((ext_vector_type(2))) u16 u16x2;
typedef __attribute__((ext_vector_type(4))) u16 u16x4;
typedef __attribute__((ext_vector_type(8))) short s16x8;
typedef __attribute__((ext_vector_type(4))) float f32x4;

__device__ __forceinline__ float leaky(float x) { return x > 0.f ? x : NEG_SLOPE * x; }

// bf16 split helpers (round-to-nearest-even on the hi part; lo captures the remainder)
__device__ __forceinline__ u16 bfhi(float f) {
  unsigned u = __float_as_uint(f);
  return (u16)((u + 0x7FFFu + ((u >> 16) & 1u)) >> 16);
}
__device__ __forceinline__ float bf2f(u16 h) { return __uint_as_float((unsigned)h << 16); }
__device__ __forceinline__ void bfsplit(float f, u16& h, u16& l) {
  h = bfhi(f);
  l = bfhi(f - bf2f(h));
}

// ---------------- CSR build ----------------
__global__ void hist_kernel(const int* __restrict__ dst, int* __restrict__ deg, int E) {
  int e = blockIdx.x * blockDim.x + threadIdx.x;
  if (e < E) atomicAdd(&deg[dst[e]], 1);
}

__global__ void scan1_kernel(const int* __restrict__ deg, int* __restrict__ exc,
                             int* __restrict__ bsum, int N) {
  __shared__ int sm[512];
  int t = threadIdx.x;
  int i = blockIdx.x * 512 + t;
  int v = (i < N) ? deg[i] : 0;
  sm[t] = v; __syncthreads();
  for (int o = 1; o < 512; o <<= 1) {
    int x = (t >= o) ? sm[t - o] : 0;
    __syncthreads();
    sm[t] += x;
    __syncthreads();
  }
  if (i < N) exc[i] = sm[t] - v;
  if (t == 511) bsum[blockIdx.x] = sm[511];
}

__global__ void scan2_kernel(const int* __restrict__ bsum, int* __restrict__ bbase, int nb) {
  __shared__ int sm[256];
  int t = threadIdx.x;
  int v = (t < nb) ? bsum[t] : 0;
  sm[t] = v; __syncthreads();
  for (int o = 1; o < 256; o <<= 1) {
    int x = (t >= o) ? sm[t - o] : 0;
    __syncthreads();
    sm[t] += x;
    __syncthreads();
  }
  if (t < nb) bbase[t] = sm[t] - v;
}

__global__ void scan3_kernel(const int* __restrict__ exc, const int* __restrict__ bbase,
                             int* __restrict__ off, int* __restrict__ cur, int N, int E) {
  int i = blockIdx.x * blockDim.x + threadIdx.x;
  if (i < N) {
    int v = exc[i] + bbase[i >> 9];
    off[i] = v;
    cur[i] = v;
  }
  if (i == 0) off[N] = E;
}

__global__ void scatter_kernel(const int* __restrict__ src, const int* __restrict__ dst,
                               int* __restrict__ cur, int* __restrict__ es, int E) {
  int e = blockIdx.x * blockDim.x + threadIdx.x;
  if (e < E) {
    int p = atomicAdd(&cur[dst[e]], 1);
    es[p] = src[e];
  }
}

// ---------------- W -> fragment-order bf16 hi/lo ----------------
__global__ void wconv_kernel(const float* __restrict__ W, u16* __restrict__ Bh,
                             u16* __restrict__ Bl, int K, int N) {
  int lane = threadIdx.x & 63;
  int blk = blockIdx.x;  // ks * (N/16) + fn
  int Nf = N >> 4;
  int ks = blk / Nf, fn = blk - ks * Nf;
  int col = fn * 16 + (lane & 15);
  int k0 = ks * 32 + (lane >> 4) * 8;
  u16 hh[8], ll[8];
#pragma unroll
  for (int j = 0; j < 8; ++j) {
    float f = W[(size_t)(k0 + j) * N + col];
    bfsplit(f, hh[j], ll[j]);
  }
  size_t o = ((size_t)blk * 64 + lane) * 8;
#pragma unroll
  for (int j = 0; j < 8; ++j) {
    Bh[o + j] = hh[j];
    Bl[o + j] = ll[j];
  }
}

// ---------------- MFMA GEMM with bf16 hi/lo error compensation ----------------
// BF16OUT=true: store C as bf16 (Cc); else fp32 (C).
template <bool CONVERT, bool BF16OUT>
__global__ __launch_bounds__(256) void gemm_mfma(
    const float* __restrict__ Af, const u16* __restrict__ Ahg, const u16* __restrict__ Alg,
    const u16* __restrict__ Bhg, const u16* __restrict__ Blg,
    float* __restrict__ C, u16* __restrict__ Cc, int M, int N, int K) {
  __shared__ u16 Ah[8 * 512];  // 8 sub-tiles x 64 lanes x 8 bf16 (fragment order)
  __shared__ u16 Al[8 * 512];
  int tid = threadIdx.x;
  int lane = tid & 63;
  int wid = tid >> 6;
  int wr = wid >> 1, wc = wid & 1;
  int bm = blockIdx.x * 128;
  int bn = blockIdx.y * 128;
  int Nf = N >> 4;
  f32x4 acc[4][4] = {};

  for (int ks = 0; ks < K; ks += 32) {
    __syncthreads();
    if constexpr (CONVERT) {
#pragma unroll
      for (int i = 0; i < 4; ++i) {
        int c = tid + (i << 8);
        int row = c >> 3, kq = c & 7;
        float4 v = make_float4(0.f, 0.f, 0.f, 0.f);
        if (bm + row < M) v = *(const float4*)&Af[(size_t)(bm + row) * K + ks + kq * 4];
        u16 hx, lx, hy, ly, hz, lz, hw, lw;
        bfsplit(v.x, hx, lx); bfsplit(v.y, hy, ly);
        bfsplit(v.z, hz, lz); bfsplit(v.w, hw, lw);
        int off = (row >> 4) * 512 + ((row & 15) + ((kq >> 1) << 4)) * 8 + (kq & 1) * 4;
        u16x4 hv = {hx, hy, hz, hw};
        u16x4 lv = {lx, ly, lz, lw};
        *(u16x4*)&Ah[off] = hv;
        *(u16x4*)&Al[off] = lv;
      }
    } else {
#pragma unroll
      for (int i = 0; i < 2; ++i) {
        int c = tid + (i << 8);
        int row = c >> 2, k8 = c & 3;
        size_t g = (size_t)(bm + row) * K + ks + k8 * 8;
        int off = (row >> 4) * 512 + ((row & 15) + (k8 << 4)) * 8;
        *(s16x8*)&Ah[off] = *(const s16x8*)&Ahg[g];
        *(s16x8*)&Al[off] = *(const s16x8*)&Alg[g];
      }
    }
    __syncthreads();

    s16x8 bh[4], bl[4];
    int ksi = ks >> 5;
#pragma unroll
    for (int fn = 0; fn < 4; ++fn) {
      int fnG = (bn >> 4) + wc * 4 + fn;
      size_t idx = (((size_t)ksi * Nf + fnG) * 64 + lane) * 8;
      bh[fn] = *(const s16x8*)&Bhg[idx];
      bl[fn] = *(const s16x8*)&Blg[idx];
    }
#pragma unroll
    for (int fm = 0; fm < 4; ++fm) {
      int st = wr * 4 + fm;
      s16x8 ah = *(const s16x8*)&Ah[st * 512 + lane * 8];
      s16x8 al = *(const s16x8*)&Al[st * 512 + lane * 8];
#pragma unroll
      for (int fn = 0; fn < 4; ++fn) {
        acc[fm][fn] = __builtin_amdgcn_mfma_f32_16x16x32_bf16(ah, bh[fn], acc[fm][fn], 0, 0, 0);
        acc[fm][fn] = __builtin_amdgcn_mfma_f32_16x16x32_bf16(ah, bl[fn], acc[fm][fn], 0, 0, 0);
        acc[fm][fn] = __builtin_amdgcn_mfma_f32_16x16x32_bf16(al, bh[fn], acc[fm][fn], 0, 0, 0);
      }
    }
  }
  // epilogue: C/D layout col = lane&15, row = (lane>>4)*4 + reg
#pragma unroll
  for (int fm = 0; fm < 4; ++fm) {
#pragma unroll
    for (int fn = 0; fn < 4; ++fn) {
#pragma unroll
      for (int r = 0; r < 4; ++r) {
        int row = bm + wr * 64 + fm * 16 + (lane >> 4) * 4 + r;
        int col = bn + wc * 64 + fn * 16 + (lane & 15);
        if (row < M) {
          if constexpr (BF16OUT) {
            Cc[(size_t)row * N + col] = bfhi(acc[fm][fn][r]);
          } else {
            C[(size_t)row * N + col] = acc[fm][fn][r];
          }
        }
      }
    }
  }
}

// ---------------- attention dots: one wave per node, coalesced full-row read ----------------
// BF16IN: h rows are bf16; else fp32.
template <int C, bool BF16IN>
__global__ __launch_bounds__(256) void adot_kernel(const void* __restrict__ h_,
                                                   const float* __restrict__ att_src,
                                                   const float* __restrict__ att_dst,
                                                   float* __restrict__ a_src,
                                                   float* __restrict__ a_dst, int N) {
  int w = (blockIdx.x * 256 + threadIdx.x) >> 6;
  int lane = threadIdx.x & 63;
  if (w >= N) return;
  int head = lane >> 4;
  int l16 = lane & 15;
  float s, d;
  if constexpr (C == 32) {
    float h0, h1v;
    if constexpr (BF16IN) {
      u16x2 hv = *(const u16x2*)&((const u16*)h_)[(size_t)w * 128 + lane * 2];
      h0 = bf2f(hv.x); h1v = bf2f(hv.y);
    } else {
      float2 hv = *(const float2*)&((const float*)h_)[(size_t)w * 128 + lane * 2];
      h0 = hv.x; h1v = hv.y;
    }
    float2 sv = *(const float2*)&att_src[head * 32 + l16 * 2];
    float2 dv = *(const float2*)&att_dst[head * 32 + l16 * 2];
    s = h0 * sv.x + h1v * sv.y;
    d = h0 * dv.x + h1v * dv.y;
  } else {
    float4 hv = *(const float4*)&((const float*)h_)[(size_t)w * 256 + lane * 4];
    float4 sv = *(const float4*)&att_src[head * 64 + l16 * 4];
    float4 dv = *(const float4*)&att_dst[head * 64 + l16 * 4];
    s = hv.x * sv.x + hv.y * sv.y + hv.z * sv.z + hv.w * sv.w;
    d = hv.x * dv.x + hv.y * dv.y + hv.z * dv.z + hv.w * dv.w;
  }
#pragma unroll
  for (int o = 1; o < 16; o <<= 1) {
    s += __shfl_xor(s, o);
    d += __shfl_xor(d, o);
  }
  if (l16 == 0) {
    a_src[(size_t)w * 4 + head] = s;
    a_dst[(size_t)w * 4 + head] = d;
  }
}

// ---------------- h2 fp32 -> bf16 compact copy ----------------
__global__ __launch_bounds__(256) void h2c_kernel(const float* __restrict__ h2,
                                                  u16* __restrict__ h2c, long total4) {
  long g = (long)blockIdx.x * 256 + threadIdx.x;
  if (g >= total4) return;
  float4 v = *(const float4*)&h2[g * 4];
  u16x4 o = {bfhi(v.x), bfhi(v.y), bfhi(v.z), bfhi(v.w)};
  *(u16x4*)&h2c[g * 4] = o;
}

// ---------------- layer-1 aggregation: bf16 gather; writes x2 as bf16 hi/lo ----------------
__global__ __launch_bounds__(256) void agg1_kernel(
    const u16* __restrict__ h1c, const float* __restrict__ asrc, const float* __restrict__ adst,
    const int* __restrict__ off, const int* __restrict__ es,
    const float* __restrict__ b1, u16* __restrict__ x2h, u16* __restrict__ x2l, int N) {
  int n = (blockIdx.x * 256 + threadIdx.x) >> 6;
  int lane = threadIdx.x & 63;
  if (n >= N) return;
  int beg = off[n], end = off[n + 1];
  int myh = lane >> 4;
  float admy = adst[(size_t)n * 4 + myh];
  float sum = 0.f;
  float2 acc = make_float2(0.f, 0.f);
  for (int j = beg; j < end; ++j) {
    int se = es[j];
    float w = __expf(leaky(asrc[(size_t)se * 4 + myh] + admy));
    sum += w;
    u16x2 hv = *(const u16x2*)&h1c[(size_t)se * 128 + lane * 2];
    acc.x += w * bf2f(hv.x);
    acc.y += w * bf2f(hv.y);
  }
  float rs = 1.f / sum;
  int c = lane * 2;
  float2 bv = *(const float2*)&b1[c];
  float y0 = acc.x * rs + bv.x;
  float y1 = acc.y * rs + bv.y;
  y0 = y0 > 0.f ? y0 : expm1f(y0);  // ELU
  y1 = y1 > 0.f ? y1 : expm1f(y1);
  u16 h0, l0, h1b, l1b;
  bfsplit(y0, h0, l0);
  bfsplit(y1, h1b, l1b);
  u16x2 hw = {h0, h1b};
  u16x2 lw = {l0, l1b};
  *(u16x2*)&x2h[(size_t)n * 128 + c] = hw;
  *(u16x2*)&x2l[(size_t)n * 128 + c] = lw;
}

// ---------------- layer-2 aggregation: bf16 gather + fused head-mean + bias ----------------
__global__ __launch_bounds__(256) void agg2_kernel(
    const u16* __restrict__ h2c, const float* __restrict__ asrc, const float* __restrict__ adst,
    const int* __restrict__ off, const int* __restrict__ es,
    const float* __restrict__ b2, float* __restrict__ out, int N) {
  int n = (blockIdx.x * 256 + threadIdx.x) >> 6;
  int lane = threadIdx.x & 63;
  if (n >= N) return;
  int beg = off[n], end = off[n + 1];
  int myh = lane >> 4;
  float admy = adst[(size_t)n * 4 + myh];
  float sum = 0.f;
  float4 acc = make_float4(0.f, 0.f, 0.f, 0.f);
  for (int j = beg; j < end; ++j) {
    int se = es[j];
    float w = __expf(leaky(asrc[(size_t)se * 4 + myh] + admy));
    sum += w;
    u16x4 hv = *(const u16x4*)&h2c[(size_t)se * 256 + lane * 4];
    acc.x += w * bf2f(hv.x);
    acc.y += w * bf2f(hv.y);
    acc.z += w * bf2f(hv.z);
    acc.w += w * bf2f(hv.w);
  }
  float rs = 1.f / sum;
  acc.x *= rs; acc.y *= rs; acc.z *= rs; acc.w *= rs;
#pragma unroll
  for (int d = 16; d < 64; d <<= 1) {
    acc.x += __shfl_xor(acc.x, d);
    acc.y += __shfl_xor(acc.y, d);
    acc.z += __shfl_xor(acc.z, d);
    acc.w += __shfl_xor(acc.w, d);
  }
  if (lane < 16) {
    int c = lane * 4;
    float4 bv = *(const float4*)&b2[c];
    float4 o;
    o.x = acc.x * 0.25f + bv.x;
    o.y = acc.y * 0.25f + bv.y;
    o.z = acc.z * 0.25f + bv.z;
    o.w = acc.w * 0.25f + bv.w;
    *(float4*)&out[(size_t)n * 64 + c] = o;
  }
}

static inline int ceil_div(int a, int b) { return (a + b - 1) / b; }

extern "C" void kernel_launch(void* const* d_in, const int* in_sizes, int n_in,
                              void* d_out, int out_size, void* d_ws, size_t ws_size,
                              hipStream_t stream) {
  const float* x = (const float*)d_in[0];
  const int* src = (const int*)d_in[1];
  const int* dst = (const int*)d_in[2];
  const float* W1 = (const float*)d_in[3];
  const float* att_src1 = (const float*)d_in[4];
  const float* att_dst1 = (const float*)d_in[5];
  const float* b1 = (const float*)d_in[6];
  const float* W2 = (const float*)d_in[7];
  const float* att_src2 = (const float*)d_in[8];
  const float* att_dst2 = (const float*)d_in[9];
  const float* b2 = (const float*)d_in[10];
  float* out = (float*)d_out;

  const int N = in_sizes[0] / 512;        // 100000 nodes
  const int E = in_sizes[1];              // 1700000 edges
  const int MP = ceil_div(N, 128) * 128;  // padded rows for 128-tall tiles

  // -------- workspace layout (~193 MB, < R3-proven 212 MB) --------
  char* ws = (char*)d_ws;
  size_t o = 0;
  auto alloc = [&](size_t bytes) -> void* {
    o = (o + 255) & ~(size_t)255;
    void* p = ws + o;
    o += bytes;
    return p;
  };
  // region A: h2 fp32 (N*256).
  float* h2 = (float*)alloc((size_t)N * 256 * 4);
  // region B: h1c bf16 (N*128), written by gemm1 epilogue, read by adot1 + agg1.
  u16* h1c = (u16*)alloc((size_t)N * 128 * 2);
  // region C: x2h + x2l (MP*128 bf16 each, contiguous). CSR temporaries alias x2h head
  // (dead before agg1 writes x2h). h2c bf16 (N*256) aliases x2h+x2l — both dead after
  // gemm2 reads them; h2c written after gemm2, read by agg2.
  u16* x2h = (u16*)alloc((size_t)MP * 128 * 2);
  u16* x2l = (u16*)alloc((size_t)MP * 128 * 2);
  u16* h2c = x2h;  // spans x2h..x2l
  int* deg = (int*)x2h;
  int* exc = deg + N;
  int* cur = exc + N;
  int* bsum = cur + N;      // 256 ints
  int* bbase = bsum + 256;  // 256 ints
  // persistent buffers
  float* as1 = (float*)alloc((size_t)N * 4 * 4);
  float* ad1 = (float*)alloc((size_t)N * 4 * 4);
  float* as2 = (float*)alloc((size_t)N * 4 * 4);
  float* ad2 = (float*)alloc((size_t)N * 4 * 4);
  int* off = (int*)alloc((size_t)(N + 1) * 4);
  int* es = (int*)alloc((size_t)E * 4);
  // fragment-order bf16 hi/lo weight panels
  u16* Bh1 = (u16*)alloc((size_t)512 * 128 * 2);
  u16* Bl1 = (u16*)alloc((size_t)512 * 128 * 2);
  u16* Bh2 = (u16*)alloc((size_t)128 * 256 * 2);
  u16* Bl2 = (u16*)alloc((size_t)128 * 256 * 2);

  const int nb = ceil_div(N, 512);  // 196 (<=256 -> single scan2 block)

  // -------- weight conversion (tiny) --------
  wconv_kernel<<<(512 / 32) * (128 / 16), 64, 0, stream>>>(W1, Bh1, Bl1, 512, 128);
  wconv_kernel<<<(128 / 32) * (256 / 16), 64, 0, stream>>>(W2, Bh2, Bl2, 128, 256);

  // -------- zero x2 padding rows (rows N..MP-1 read unguarded by gemm2's A-load) --------
  hipMemsetAsync(x2h + (size_t)N * 128, 0, (size_t)(MP - N) * 128 * 2, stream);
  hipMemsetAsync(x2l + (size_t)N * 128, 0, (size_t)(MP - N) * 128 * 2, stream);

  // -------- CSR build (shared by both layers) --------
  hipMemsetAsync(deg, 0, (size_t)N * 4, stream);
  hist_kernel<<<ceil_div(E, 256), 256, 0, stream>>>(dst, deg, E);
  scan1_kernel<<<nb, 512, 0, stream>>>(deg, exc, bsum, N);
  scan2_kernel<<<1, 256, 0, stream>>>(bsum, bbase, nb);
  scan3_kernel<<<ceil_div(N, 256), 256, 0, stream>>>(exc, bbase, off, cur, N, E);
  scatter_kernel<<<ceil_div(E, 256), 256, 0, stream>>>(src, dst, cur, es, E);

  // -------- layer 1 (h1 stored bf16-only) --------
  gemm_mfma<true, true><<<dim3(MP / 128, 1), 256, 0, stream>>>(
      x, nullptr, nullptr, Bh1, Bl1, nullptr, h1c, N, 128, 512);
  adot_kernel<32, true><<<ceil_div(N * 64, 256), 256, 0, stream>>>(
      h1c, att_src1, att_dst1, as1, ad1, N);
  agg1_kernel<<<ceil_div(N, 4), 256, 0, stream>>>(h1c, as1, ad1, off, es, b1, x2h, x2l, N);

  // -------- layer 2 --------
  gemm_mfma<false, false><<<dim3(MP / 128, 2), 256, 0, stream>>>(
      nullptr, x2h, x2l, Bh2, Bl2, h2, nullptr, N, 256, 128);
  adot_kernel<64, false><<<ceil_div(N * 64, 256), 256, 0, stream>>>(
      h2, att_src2, att_dst2, as2, ad2, N);
  h2c_kernel<<<ceil_div(N * 64, 256), 256, 0, stream>>>(h2, h2c, (long)N * 64);
  agg2_kernel<<<ceil_div(N, 4), 256, 0, stream>>>(h2c, as2, ad2, off, es, b2, out, N);
}

// Round 8
// 853.549 us; speedup vs baseline: 1.4165x; 1.2122x over previous
//
#include <hip/hip_runtime.h>
#include <hip/hip_bf16.h>
#include <math.h>

#define NEG_SLOPE 0.2f

using u16 = unsigned short;
typedef __attribute__((ext_vector_type(2))) u16 u16x2;
typedef __attribute__((ext_vector_type(4))) u16 u16x4;
typedef __attribute__((ext_vector_type(8))) short s16x8;
typedef __attribute__((ext_vector_type(4))) float f32x4;

__device__ __forceinline__ float leaky(float x) { return x > 0.f ? x : NEG_SLOPE * x; }

// bf16 split helpers (round-to-nearest-even on the hi part; lo captures the remainder)
__device__ __forceinline__ u16 bfhi(float f) {
  unsigned u = __float_as_uint(f);
  return (u16)((u + 0x7FFFu + ((u >> 16) & 1u)) >> 16);
}
__device__ __forceinline__ float bf2f(u16 h) { return __uint_as_float((unsigned)h << 16); }
__device__ __forceinline__ void bfsplit(float f, u16& h, u16& l) {
  h = bfhi(f);
  l = bfhi(f - bf2f(h));
}

// ---------------- CSR build ----------------
__global__ void hist_kernel(const int* __restrict__ dst, int* __restrict__ deg, int E) {
  int e = blockIdx.x * blockDim.x + threadIdx.x;
  if (e < E) atomicAdd(&deg[dst[e]], 1);
}

__global__ void scan1_kernel(const int* __restrict__ deg, int* __restrict__ exc,
                             int* __restrict__ bsum, int N) {
  __shared__ int sm[512];
  int t = threadIdx.x;
  int i = blockIdx.x * 512 + t;
  int v = (i < N) ? deg[i] : 0;
  sm[t] = v; __syncthreads();
  for (int o = 1; o < 512; o <<= 1) {
    int x = (t >= o) ? sm[t - o] : 0;
    __syncthreads();
    sm[t] += x;
    __syncthreads();
  }
  if (i < N) exc[i] = sm[t] - v;
  if (t == 511) bsum[blockIdx.x] = sm[511];
}

__global__ void scan2_kernel(const int* __restrict__ bsum, int* __restrict__ bbase, int nb) {
  __shared__ int sm[256];
  int t = threadIdx.x;
  int v = (t < nb) ? bsum[t] : 0;
  sm[t] = v; __syncthreads();
  for (int o = 1; o < 256; o <<= 1) {
    int x = (t >= o) ? sm[t - o] : 0;
    __syncthreads();
    sm[t] += x;
    __syncthreads();
  }
  if (t < nb) bbase[t] = sm[t] - v;
}

__global__ void scan3_kernel(const int* __restrict__ exc, const int* __restrict__ bbase,
                             int* __restrict__ off, int* __restrict__ cur, int N, int E) {
  int i = blockIdx.x * blockDim.x + threadIdx.x;
  if (i < N) {
    int v = exc[i] + bbase[i >> 9];
    off[i] = v;
    cur[i] = v;
  }
  if (i == 0) off[N] = E;
}

__global__ void scatter_kernel(const int* __restrict__ src, const int* __restrict__ dst,
                               int* __restrict__ cur, int* __restrict__ es, int E) {
  int e = blockIdx.x * blockDim.x + threadIdx.x;
  if (e < E) {
    int p = atomicAdd(&cur[dst[e]], 1);
    es[p] = src[e];
  }
}

// ---------------- W -> fragment-order bf16 hi/lo ----------------
__global__ void wconv_kernel(const float* __restrict__ W, u16* __restrict__ Bh,
                             u16* __restrict__ Bl, int K, int N) {
  int lane = threadIdx.x & 63;
  int blk = blockIdx.x;  // ks * (N/16) + fn
  int Nf = N >> 4;
  int ks = blk / Nf, fn = blk - ks * Nf;
  int col = fn * 16 + (lane & 15);
  int k0 = ks * 32 + (lane >> 4) * 8;
  u16 hh[8], ll[8];
#pragma unroll
  for (int j = 0; j < 8; ++j) {
    float f = W[(size_t)(k0 + j) * N + col];
    bfsplit(f, hh[j], ll[j]);
  }
  size_t o = ((size_t)blk * 64 + lane) * 8;
#pragma unroll
  for (int j = 0; j < 8; ++j) {
    Bh[o + j] = hh[j];
    Bl[o + j] = ll[j];
  }
}

// ---------------- MFMA GEMM with bf16 hi/lo error compensation ----------------
// BF16OUT=true: store C as bf16 (Cc); else fp32 (C).
template <bool CONVERT, bool BF16OUT>
__global__ __launch_bounds__(256) void gemm_mfma(
    const float* __restrict__ Af, const u16* __restrict__ Ahg, const u16* __restrict__ Alg,
    const u16* __restrict__ Bhg, const u16* __restrict__ Blg,
    float* __restrict__ C, u16* __restrict__ Cc, int M, int N, int K) {
  __shared__ u16 Ah[8 * 512];  // 8 sub-tiles x 64 lanes x 8 bf16 (fragment order)
  __shared__ u16 Al[8 * 512];
  int tid = threadIdx.x;
  int lane = tid & 63;
  int wid = tid >> 6;
  int wr = wid >> 1, wc = wid & 1;
  int bm = blockIdx.x * 128;
  int bn = blockIdx.y * 128;
  int Nf = N >> 4;
  f32x4 acc[4][4] = {};

  for (int ks = 0; ks < K; ks += 32) {
    __syncthreads();
    if constexpr (CONVERT) {
#pragma unroll
      for (int i = 0; i < 4; ++i) {
        int c = tid + (i << 8);
        int row = c >> 3, kq = c & 7;
        float4 v = make_float4(0.f, 0.f, 0.f, 0.f);
        if (bm + row < M) v = *(const float4*)&Af[(size_t)(bm + row) * K + ks + kq * 4];
        u16 hx, lx, hy, ly, hz, lz, hw, lw;
        bfsplit(v.x, hx, lx); bfsplit(v.y, hy, ly);
        bfsplit(v.z, hz, lz); bfsplit(v.w, hw, lw);
        int off = (row >> 4) * 512 + ((row & 15) + ((kq >> 1) << 4)) * 8 + (kq & 1) * 4;
        u16x4 hv = {hx, hy, hz, hw};
        u16x4 lv = {lx, ly, lz, lw};
        *(u16x4*)&Ah[off] = hv;
        *(u16x4*)&Al[off] = lv;
      }
    } else {
#pragma unroll
      for (int i = 0; i < 2; ++i) {
        int c = tid + (i << 8);
        int row = c >> 2, k8 = c & 3;
        size_t g = (size_t)(bm + row) * K + ks + k8 * 8;
        int off = (row >> 4) * 512 + ((row & 15) + (k8 << 4)) * 8;
        *(s16x8*)&Ah[off] = *(const s16x8*)&Ahg[g];
        *(s16x8*)&Al[off] = *(const s16x8*)&Alg[g];
      }
    }
    __syncthreads();

    s16x8 bh[4], bl[4];
    int ksi = ks >> 5;
#pragma unroll
    for (int fn = 0; fn < 4; ++fn) {
      int fnG = (bn >> 4) + wc * 4 + fn;
      size_t idx = (((size_t)ksi * Nf + fnG) * 64 + lane) * 8;
      bh[fn] = *(const s16x8*)&Bhg[idx];
      bl[fn] = *(const s16x8*)&Blg[idx];
    }
#pragma unroll
    for (int fm = 0; fm < 4; ++fm) {
      int st = wr * 4 + fm;
      s16x8 ah = *(const s16x8*)&Ah[st * 512 + lane * 8];
      s16x8 al = *(const s16x8*)&Al[st * 512 + lane * 8];
#pragma unroll
      for (int fn = 0; fn < 4; ++fn) {
        acc[fm][fn] = __builtin_amdgcn_mfma_f32_16x16x32_bf16(ah, bh[fn], acc[fm][fn], 0, 0, 0);
        acc[fm][fn] = __builtin_amdgcn_mfma_f32_16x16x32_bf16(ah, bl[fn], acc[fm][fn], 0, 0, 0);
        acc[fm][fn] = __builtin_amdgcn_mfma_f32_16x16x32_bf16(al, bh[fn], acc[fm][fn], 0, 0, 0);
      }
    }
  }
  // epilogue: C/D layout col = lane&15, row = (lane>>4)*4 + reg
#pragma unroll
  for (int fm = 0; fm < 4; ++fm) {
#pragma unroll
    for (int fn = 0; fn < 4; ++fn) {
#pragma unroll
      for (int r = 0; r < 4; ++r) {
        int row = bm + wr * 64 + fm * 16 + (lane >> 4) * 4 + r;
        int col = bn + wc * 64 + fn * 16 + (lane & 15);
        if (row < M) {
          if constexpr (BF16OUT) {
            Cc[(size_t)row * N + col] = bfhi(acc[fm][fn][r]);
          } else {
            C[(size_t)row * N + col] = acc[fm][fn][r];
          }
        }
      }
    }
  }
}

// ---------------- attention dots: one wave per node, coalesced full-row read ----------------
// BF16IN: h rows are bf16; else fp32.
template <int C, bool BF16IN>
__global__ __launch_bounds__(256) void adot_kernel(const void* __restrict__ h_,
                                                   const float* __restrict__ att_src,
                                                   const float* __restrict__ att_dst,
                                                   float* __restrict__ a_src,
                                                   float* __restrict__ a_dst, int N) {
  int w = (blockIdx.x * 256 + threadIdx.x) >> 6;
  int lane = threadIdx.x & 63;
  if (w >= N) return;
  int head = lane >> 4;
  int l16 = lane & 15;
  float s, d;
  if constexpr (C == 32) {
    float h0, h1v;
    if constexpr (BF16IN) {
      u16x2 hv = *(const u16x2*)&((const u16*)h_)[(size_t)w * 128 + lane * 2];
      h0 = bf2f(hv.x); h1v = bf2f(hv.y);
    } else {
      float2 hv = *(const float2*)&((const float*)h_)[(size_t)w * 128 + lane * 2];
      h0 = hv.x; h1v = hv.y;
    }
    float2 sv = *(const float2*)&att_src[head * 32 + l16 * 2];
    float2 dv = *(const float2*)&att_dst[head * 32 + l16 * 2];
    s = h0 * sv.x + h1v * sv.y;
    d = h0 * dv.x + h1v * dv.y;
  } else {
    float h0, h1v, h2v, h3v;
    if constexpr (BF16IN) {
      u16x4 hv = *(const u16x4*)&((const u16*)h_)[(size_t)w * 256 + lane * 4];
      h0 = bf2f(hv.x); h1v = bf2f(hv.y); h2v = bf2f(hv.z); h3v = bf2f(hv.w);
    } else {
      float4 hv = *(const float4*)&((const float*)h_)[(size_t)w * 256 + lane * 4];
      h0 = hv.x; h1v = hv.y; h2v = hv.z; h3v = hv.w;
    }
    float4 sv = *(const float4*)&att_src[head * 64 + l16 * 4];
    float4 dv = *(const float4*)&att_dst[head * 64 + l16 * 4];
    s = h0 * sv.x + h1v * sv.y + h2v * sv.z + h3v * sv.w;
    d = h0 * dv.x + h1v * dv.y + h2v * dv.z + h3v * dv.w;
  }
#pragma unroll
  for (int o = 1; o < 16; o <<= 1) {
    s += __shfl_xor(s, o);
    d += __shfl_xor(d, o);
  }
  if (l16 == 0) {
    a_src[(size_t)w * 4 + head] = s;
    a_dst[(size_t)w * 4 + head] = d;
  }
}

// ---------------- layer-1 aggregation: bf16 gather (unroll-4); writes x2 bf16 hi/lo ----------------
__global__ __launch_bounds__(256) void agg1_kernel(
    const u16* __restrict__ h1c, const float* __restrict__ asrc, const float* __restrict__ adst,
    const int* __restrict__ off, const int* __restrict__ es,
    const float* __restrict__ b1, u16* __restrict__ x2h, u16* __restrict__ x2l, int N) {
  int n = (blockIdx.x * 256 + threadIdx.x) >> 6;
  int lane = threadIdx.x & 63;
  if (n >= N) return;
  int beg = off[n], end = off[n + 1];
  int myh = lane >> 4;
  float admy = adst[(size_t)n * 4 + myh];
  float sum = 0.f;
  float2 acc = make_float2(0.f, 0.f);
  int j = beg;
  for (; j + 3 < end; j += 4) {
    int se0 = es[j], se1 = es[j + 1], se2 = es[j + 2], se3 = es[j + 3];
    u16x2 r0 = *(const u16x2*)&h1c[(size_t)se0 * 128 + lane * 2];
    u16x2 r1 = *(const u16x2*)&h1c[(size_t)se1 * 128 + lane * 2];
    u16x2 r2 = *(const u16x2*)&h1c[(size_t)se2 * 128 + lane * 2];
    u16x2 r3 = *(const u16x2*)&h1c[(size_t)se3 * 128 + lane * 2];
    float w0 = __expf(leaky(asrc[(size_t)se0 * 4 + myh] + admy));
    float w1 = __expf(leaky(asrc[(size_t)se1 * 4 + myh] + admy));
    float w2 = __expf(leaky(asrc[(size_t)se2 * 4 + myh] + admy));
    float w3 = __expf(leaky(asrc[(size_t)se3 * 4 + myh] + admy));
    sum += w0; acc.x += w0 * bf2f(r0.x); acc.y += w0 * bf2f(r0.y);
    sum += w1; acc.x += w1 * bf2f(r1.x); acc.y += w1 * bf2f(r1.y);
    sum += w2; acc.x += w2 * bf2f(r2.x); acc.y += w2 * bf2f(r2.y);
    sum += w3; acc.x += w3 * bf2f(r3.x); acc.y += w3 * bf2f(r3.y);
  }
  for (; j < end; ++j) {
    int se = es[j];
    float w = __expf(leaky(asrc[(size_t)se * 4 + myh] + admy));
    sum += w;
    u16x2 hv = *(const u16x2*)&h1c[(size_t)se * 128 + lane * 2];
    acc.x += w * bf2f(hv.x);
    acc.y += w * bf2f(hv.y);
  }
  float rs = 1.f / sum;
  int c = lane * 2;
  float2 bv = *(const float2*)&b1[c];
  float y0 = acc.x * rs + bv.x;
  float y1 = acc.y * rs + bv.y;
  y0 = y0 > 0.f ? y0 : expm1f(y0);  // ELU
  y1 = y1 > 0.f ? y1 : expm1f(y1);
  u16 h0, l0, h1b, l1b;
  bfsplit(y0, h0, l0);
  bfsplit(y1, h1b, l1b);
  u16x2 hw = {h0, h1b};
  u16x2 lw = {l0, l1b};
  *(u16x2*)&x2h[(size_t)n * 128 + c] = hw;
  *(u16x2*)&x2l[(size_t)n * 128 + c] = lw;
}

// ---------------- layer-2 aggregation: bf16 gather (unroll-4) + fused head-mean + bias ----------------
__global__ __launch_bounds__(256) void agg2_kernel(
    const u16* __restrict__ h2c, const float* __restrict__ asrc, const float* __restrict__ adst,
    const int* __restrict__ off, const int* __restrict__ es,
    const float* __restrict__ b2, float* __restrict__ out, int N) {
  int n = (blockIdx.x * 256 + threadIdx.x) >> 6;
  int lane = threadIdx.x & 63;
  if (n >= N) return;
  int beg = off[n], end = off[n + 1];
  int myh = lane >> 4;
  float admy = adst[(size_t)n * 4 + myh];
  float sum = 0.f;
  float4 acc = make_float4(0.f, 0.f, 0.f, 0.f);
  int j = beg;
  for (; j + 3 < end; j += 4) {
    int se0 = es[j], se1 = es[j + 1], se2 = es[j + 2], se3 = es[j + 3];
    u16x4 r0 = *(const u16x4*)&h2c[(size_t)se0 * 256 + lane * 4];
    u16x4 r1 = *(const u16x4*)&h2c[(size_t)se1 * 256 + lane * 4];
    u16x4 r2 = *(const u16x4*)&h2c[(size_t)se2 * 256 + lane * 4];
    u16x4 r3 = *(const u16x4*)&h2c[(size_t)se3 * 256 + lane * 4];
    float w0 = __expf(leaky(asrc[(size_t)se0 * 4 + myh] + admy));
    float w1 = __expf(leaky(asrc[(size_t)se1 * 4 + myh] + admy));
    float w2 = __expf(leaky(asrc[(size_t)se2 * 4 + myh] + admy));
    float w3 = __expf(leaky(asrc[(size_t)se3 * 4 + myh] + admy));
    sum += w0;
    acc.x += w0 * bf2f(r0.x); acc.y += w0 * bf2f(r0.y);
    acc.z += w0 * bf2f(r0.z); acc.w += w0 * bf2f(r0.w);
    sum += w1;
    acc.x += w1 * bf2f(r1.x); acc.y += w1 * bf2f(r1.y);
    acc.z += w1 * bf2f(r1.z); acc.w += w1 * bf2f(r1.w);
    sum += w2;
    acc.x += w2 * bf2f(r2.x); acc.y += w2 * bf2f(r2.y);
    acc.z += w2 * bf2f(r2.z); acc.w += w2 * bf2f(r2.w);
    sum += w3;
    acc.x += w3 * bf2f(r3.x); acc.y += w3 * bf2f(r3.y);
    acc.z += w3 * bf2f(r3.z); acc.w += w3 * bf2f(r3.w);
  }
  for (; j < end; ++j) {
    int se = es[j];
    float w = __expf(leaky(asrc[(size_t)se * 4 + myh] + admy));
    sum += w;
    u16x4 hv = *(const u16x4*)&h2c[(size_t)se * 256 + lane * 4];
    acc.x += w * bf2f(hv.x);
    acc.y += w * bf2f(hv.y);
    acc.z += w * bf2f(hv.z);
    acc.w += w * bf2f(hv.w);
  }
  float rs = 1.f / sum;
  acc.x *= rs; acc.y *= rs; acc.z *= rs; acc.w *= rs;
#pragma unroll
  for (int d = 16; d < 64; d <<= 1) {
    acc.x += __shfl_xor(acc.x, d);
    acc.y += __shfl_xor(acc.y, d);
    acc.z += __shfl_xor(acc.z, d);
    acc.w += __shfl_xor(acc.w, d);
  }
  if (lane < 16) {
    int c = lane * 4;
    float4 bv = *(const float4*)&b2[c];
    float4 o;
    o.x = acc.x * 0.25f + bv.x;
    o.y = acc.y * 0.25f + bv.y;
    o.z = acc.z * 0.25f + bv.z;
    o.w = acc.w * 0.25f + bv.w;
    *(float4*)&out[(size_t)n * 64 + c] = o;
  }
}

static inline int ceil_div(int a, int b) { return (a + b - 1) / b; }

extern "C" void kernel_launch(void* const* d_in, const int* in_sizes, int n_in,
                              void* d_out, int out_size, void* d_ws, size_t ws_size,
                              hipStream_t stream) {
  const float* x = (const float*)d_in[0];
  const int* src = (const int*)d_in[1];
  const int* dst = (const int*)d_in[2];
  const float* W1 = (const float*)d_in[3];
  const float* att_src1 = (const float*)d_in[4];
  const float* att_dst1 = (const float*)d_in[5];
  const float* b1 = (const float*)d_in[6];
  const float* W2 = (const float*)d_in[7];
  const float* att_src2 = (const float*)d_in[8];
  const float* att_dst2 = (const float*)d_in[9];
  const float* b2 = (const float*)d_in[10];
  float* out = (float*)d_out;

  const int N = in_sizes[0] / 512;        // 100000 nodes
  const int E = in_sizes[1];              // 1700000 edges
  const int MP = ceil_div(N, 128) * 128;  // padded rows for 128-tall tiles

  // -------- workspace layout (~140 MB). h2c has a DEDICATED region: gemm2's epilogue
  // writes it while other blocks read x2h/x2l, so it must not alias them (R5 lesson). --------
  char* ws = (char*)d_ws;
  size_t o = 0;
  auto alloc = [&](size_t bytes) -> void* {
    o = (o + 255) & ~(size_t)255;
    void* p = ws + o;
    o += bytes;
    return p;
  };
  // region A: h2c bf16 (N*256), written by gemm2 epilogue, read by adot2 + agg2.
  u16* h2c = (u16*)alloc((size_t)N * 256 * 2);
  // region B: h1c bf16 (N*128), written by gemm1 epilogue, read by adot1 + agg1.
  u16* h1c = (u16*)alloc((size_t)N * 128 * 2);
  // region C: x2h + x2l (MP*128 bf16 each). CSR temporaries alias x2h head
  // (dead before agg1 writes x2h).
  u16* x2h = (u16*)alloc((size_t)MP * 128 * 2);
  u16* x2l = (u16*)alloc((size_t)MP * 128 * 2);
  int* deg = (int*)x2h;
  int* exc = deg + N;
  int* cur = exc + N;
  int* bsum = cur + N;      // 256 ints
  int* bbase = bsum + 256;  // 256 ints
  // persistent buffers
  float* as1 = (float*)alloc((size_t)N * 4 * 4);
  float* ad1 = (float*)alloc((size_t)N * 4 * 4);
  float* as2 = (float*)alloc((size_t)N * 4 * 4);
  float* ad2 = (float*)alloc((size_t)N * 4 * 4);
  int* off = (int*)alloc((size_t)(N + 1) * 4);
  int* es = (int*)alloc((size_t)E * 4);
  // fragment-order bf16 hi/lo weight panels
  u16* Bh1 = (u16*)alloc((size_t)512 * 128 * 2);
  u16* Bl1 = (u16*)alloc((size_t)512 * 128 * 2);
  u16* Bh2 = (u16*)alloc((size_t)128 * 256 * 2);
  u16* Bl2 = (u16*)alloc((size_t)128 * 256 * 2);

  const int nb = ceil_div(N, 512);  // 196 (<=256 -> single scan2 block)

  // -------- weight conversion (tiny) --------
  wconv_kernel<<<(512 / 32) * (128 / 16), 64, 0, stream>>>(W1, Bh1, Bl1, 512, 128);
  wconv_kernel<<<(128 / 32) * (256 / 16), 64, 0, stream>>>(W2, Bh2, Bl2, 128, 256);

  // -------- zero x2 padding rows (rows N..MP-1 read unguarded by gemm2's A-load) --------
  hipMemsetAsync(x2h + (size_t)N * 128, 0, (size_t)(MP - N) * 128 * 2, stream);
  hipMemsetAsync(x2l + (size_t)N * 128, 0, (size_t)(MP - N) * 128 * 2, stream);

  // -------- CSR build (shared by both layers) --------
  hipMemsetAsync(deg, 0, (size_t)N * 4, stream);
  hist_kernel<<<ceil_div(E, 256), 256, 0, stream>>>(dst, deg, E);
  scan1_kernel<<<nb, 512, 0, stream>>>(deg, exc, bsum, N);
  scan2_kernel<<<1, 256, 0, stream>>>(bsum, bbase, nb);
  scan3_kernel<<<ceil_div(N, 256), 256, 0, stream>>>(exc, bbase, off, cur, N, E);
  scatter_kernel<<<ceil_div(E, 256), 256, 0, stream>>>(src, dst, cur, es, E);

  // -------- layer 1 (h1 stored bf16-only) --------
  gemm_mfma<true, true><<<dim3(MP / 128, 1), 256, 0, stream>>>(
      x, nullptr, nullptr, Bh1, Bl1, nullptr, h1c, N, 128, 512);
  adot_kernel<32, true><<<ceil_div(N * 64, 256), 256, 0, stream>>>(
      h1c, att_src1, att_dst1, as1, ad1, N);
  agg1_kernel<<<ceil_div(N, 4), 256, 0, stream>>>(h1c, as1, ad1, off, es, b1, x2h, x2l, N);

  // -------- layer 2 (h2 stored bf16-only, dedicated region) --------
  gemm_mfma<false, true><<<dim3(MP / 128, 2), 256, 0, stream>>>(
      nullptr, x2h, x2l, Bh2, Bl2, nullptr, h2c, N, 256, 128);
  adot_kernel<64, true><<<ceil_div(N * 64, 256), 256, 0, stream>>>(
      h2c, att_src2, att_dst2, as2, ad2, N);
  agg2_kernel<<<ceil_div(N, 4), 256, 0, stream>>>(h2c, as2, ad2, off, es, b2, out, N);
}

// Round 11
// 807.925 us; speedup vs baseline: 1.4965x; 1.0565x over previous
//
#include <hip/hip_runtime.h>
#include <hip/hip_bf16.h>
#include <math.h>

#define NEG_SLOPE 0.2f

using u16 = unsigned short;
typedef __attribute__((ext_vector_type(2))) u16 u16x2;
typedef __attribute__((ext_vector_type(4))) u16 u16x4;
typedef __attribute__((ext_vector_type(8))) short s16x8;
typedef __attribute__((ext_vector_type(4))) float f32x4;

__device__ __forceinline__ float leaky(float x) { return x > 0.f ? x : NEG_SLOPE * x; }

// bf16 split helpers (round-to-nearest-even on the hi part; lo captures the remainder)
__device__ __forceinline__ u16 bfhi(float f) {
  unsigned u = __float_as_uint(f);
  return (u16)((u + 0x7FFFu + ((u >> 16) & 1u)) >> 16);
}
__device__ __forceinline__ float bf2f(u16 h) { return __uint_as_float((unsigned)h << 16); }
__device__ __forceinline__ void bfsplit(float f, u16& h, u16& l) {
  h = bfhi(f);
  l = bfhi(f - bf2f(h));
}

// ---------------- CSR build ----------------
__global__ void hist_kernel(const int* __restrict__ dst, int* __restrict__ deg, int E) {
  int e = blockIdx.x * blockDim.x + threadIdx.x;
  if (e < E) atomicAdd(&deg[dst[e]], 1);
}

__global__ void scan1_kernel(const int* __restrict__ deg, int* __restrict__ exc,
                             int* __restrict__ bsum, int N) {
  __shared__ int sm[512];
  int t = threadIdx.x;
  int i = blockIdx.x * 512 + t;
  int v = (i < N) ? deg[i] : 0;
  sm[t] = v; __syncthreads();
  for (int o = 1; o < 512; o <<= 1) {
    int x = (t >= o) ? sm[t - o] : 0;
    __syncthreads();
    sm[t] += x;
    __syncthreads();
  }
  if (i < N) exc[i] = sm[t] - v;
  if (t == 511) bsum[blockIdx.x] = sm[511];
}

__global__ void scan2_kernel(const int* __restrict__ bsum, int* __restrict__ bbase, int nb) {
  __shared__ int sm[256];
  int t = threadIdx.x;
  int v = (t < nb) ? bsum[t] : 0;
  sm[t] = v; __syncthreads();
  for (int o = 1; o < 256; o <<= 1) {
    int x = (t >= o) ? sm[t - o] : 0;
    __syncthreads();
    sm[t] += x;
    __syncthreads();
  }
  if (t < nb) bbase[t] = sm[t] - v;
}

__global__ void scan3_kernel(const int* __restrict__ exc, const int* __restrict__ bbase,
                             int* __restrict__ off, int* __restrict__ cur, int N, int E) {
  int i = blockIdx.x * blockDim.x + threadIdx.x;
  if (i < N) {
    int v = exc[i] + bbase[i >> 9];
    off[i] = v;
    cur[i] = v;
  }
  if (i == 0) off[N] = E;
}

__global__ void scatter_kernel(const int* __restrict__ src, const int* __restrict__ dst,
                               int* __restrict__ cur, int* __restrict__ es, int E) {
  int e = blockIdx.x * blockDim.x + threadIdx.x;
  if (e < E) {
    int p = atomicAdd(&cur[dst[e]], 1);
    es[p] = src[e];
  }
}

// ---------------- W -> fragment-order bf16 hi/lo ----------------
__global__ void wconv_kernel(const float* __restrict__ W, u16* __restrict__ Bh,
                             u16* __restrict__ Bl, int K, int N) {
  int lane = threadIdx.x & 63;
  int blk = blockIdx.x;  // ks * (N/16) + fn
  int Nf = N >> 4;
  int ks = blk / Nf, fn = blk - ks * Nf;
  int col = fn * 16 + (lane & 15);
  int k0 = ks * 32 + (lane >> 4) * 8;
  u16 hh[8], ll[8];
#pragma unroll
  for (int j = 0; j < 8; ++j) {
    float f = W[(size_t)(k0 + j) * N + col];
    bfsplit(f, hh[j], ll[j]);
  }
  size_t o = ((size_t)blk * 64 + lane) * 8;
#pragma unroll
  for (int j = 0; j < 8; ++j) {
    Bh[o + j] = hh[j];
    Bl[o + j] = ll[j];
  }
}

// ---------------- MFMA GEMM, software-pipelined A staging ----------------
// 3-term bf16 hi/lo compensation: Ah*Bh + Ah*Bl + Al*Bh.
// KTOT compile-time -> K-loop fully unrolled -> reg ping-pong indices constant-fold.
// Tile k+1's global A-loads are issued right after tile k's LDS convert, so HBM
// latency hides under barrier + ds_read + MFMA of tile k.
template <bool CONVERT, bool BF16OUT, int KTOT>
__global__ __launch_bounds__(256) void gemm_mfma(
    const float* __restrict__ Af, const u16* __restrict__ Ahg, const u16* __restrict__ Alg,
    const u16* __restrict__ Bhg, const u16* __restrict__ Blg,
    float* __restrict__ C, u16* __restrict__ Cc, int M, int N) {
  constexpr int NS = KTOT / 32;
  __shared__ u16 Ah[8 * 512];  // 8 sub-tiles x 64 lanes x 8 bf16 (fragment order)
  __shared__ u16 Al[8 * 512];
  int tid = threadIdx.x;
  int lane = tid & 63;
  int wid = tid >> 6;
  int wr = wid >> 1, wc = wid & 1;
  int bm = blockIdx.x * 128;
  int bn = blockIdx.y * 128;
  int Nf = N >> 4;
  f32x4 acc[4][4] = {};

  float4 ab[2][4];            // CONVERT path ping-pong
  s16x8 hb[2][2], lb[2][2];   // pre-split path ping-pong

  // -------- prologue: stage tile 0 into regs --------
  if constexpr (CONVERT) {
#pragma unroll
    for (int i = 0; i < 4; ++i) {
      int c = tid + (i << 8);
      int row = c >> 3, kq = c & 7;
      ab[0][i] = make_float4(0.f, 0.f, 0.f, 0.f);
      if (bm + row < M) ab[0][i] = *(const float4*)&Af[(size_t)(bm + row) * KTOT + kq * 4];
    }
  } else {
#pragma unroll
    for (int i = 0; i < 2; ++i) {
      int c = tid + (i << 8);
      int row = c >> 2, k8 = c & 3;
      size_t g = (size_t)(bm + row) * KTOT + k8 * 8;
      hb[0][i] = *(const s16x8*)&Ahg[g];
      lb[0][i] = *(const s16x8*)&Alg[g];
    }
  }

#pragma unroll
  for (int ksi = 0; ksi < NS; ++ksi) {
    const int cur = ksi & 1, nxt = cur ^ 1;
    const int ks = ksi * 32;
    __syncthreads();  // previous MFMA phase done reading LDS
    if constexpr (CONVERT) {
      // convert current regs -> LDS (fragment order, same offsets as proven build)
#pragma unroll
      for (int i = 0; i < 4; ++i) {
        int c = tid + (i << 8);
        int row = c >> 3, kq = c & 7;
        float4 v = ab[cur][i];
        u16 hx, lx, hy, ly, hz, lz, hw, lw;
        bfsplit(v.x, hx, lx); bfsplit(v.y, hy, ly);
        bfsplit(v.z, hz, lz); bfsplit(v.w, hw, lw);
        int off = (row >> 4) * 512 + ((row & 15) + ((kq >> 1) << 4)) * 8 + (kq & 1) * 4;
        u16x4 hv = {hx, hy, hz, hw};
        u16x4 lv = {lx, ly, lz, lw};
        *(u16x4*)&Ah[off] = hv;
        *(u16x4*)&Al[off] = lv;
      }
      if (ksi + 1 < NS) {  // issue next tile's loads (latency hides under MFMA below)
#pragma unroll
        for (int i = 0; i < 4; ++i) {
          int c = tid + (i << 8);
          int row = c >> 3, kq = c & 7;
          ab[nxt][i] = make_float4(0.f, 0.f, 0.f, 0.f);
          if (bm + row < M)
            ab[nxt][i] = *(const float4*)&Af[(size_t)(bm + row) * KTOT + ks + 32 + kq * 4];
        }
      }
    } else {
#pragma unroll
      for (int i = 0; i < 2; ++i) {
        int c = tid + (i << 8);
        int row = c >> 2, k8 = c & 3;
        int off = (row >> 4) * 512 + ((row & 15) + (k8 << 4)) * 8;
        *(s16x8*)&Ah[off] = hb[cur][i];
        *(s16x8*)&Al[off] = lb[cur][i];
      }
      if (ksi + 1 < NS) {
#pragma unroll
        for (int i = 0; i < 2; ++i) {
          int c = tid + (i << 8);
          int row = c >> 2, k8 = c & 3;
          size_t g = (size_t)(bm + row) * KTOT + ks + 32 + k8 * 8;
          hb[nxt][i] = *(const s16x8*)&Ahg[g];
          lb[nxt][i] = *(const s16x8*)&Alg[g];
        }
      }
    }
    __syncthreads();  // LDS tile ready

    s16x8 bh[4], bl[4];
#pragma unroll
    for (int fn = 0; fn < 4; ++fn) {
      int fnG = (bn >> 4) + wc * 4 + fn;
      size_t idx = (((size_t)ksi * Nf + fnG) * 64 + lane) * 8;
      bh[fn] = *(const s16x8*)&Bhg[idx];
      bl[fn] = *(const s16x8*)&Blg[idx];
    }
#pragma unroll
    for (int fm = 0; fm < 4; ++fm) {
      int st = wr * 4 + fm;
      s16x8 ah = *(const s16x8*)&Ah[st * 512 + lane * 8];
      s16x8 al = *(const s16x8*)&Al[st * 512 + lane * 8];
#pragma unroll
      for (int fn = 0; fn < 4; ++fn) {
        acc[fm][fn] = __builtin_amdgcn_mfma_f32_16x16x32_bf16(ah, bh[fn], acc[fm][fn], 0, 0, 0);
        acc[fm][fn] = __builtin_amdgcn_mfma_f32_16x16x32_bf16(ah, bl[fn], acc[fm][fn], 0, 0, 0);
        acc[fm][fn] = __builtin_amdgcn_mfma_f32_16x16x32_bf16(al, bh[fn], acc[fm][fn], 0, 0, 0);
      }
    }
  }
  // epilogue: C/D layout col = lane&15, row = (lane>>4)*4 + reg
#pragma unroll
  for (int fm = 0; fm < 4; ++fm) {
#pragma unroll
    for (int fn = 0; fn < 4; ++fn) {
#pragma unroll
      for (int r = 0; r < 4; ++r) {
        int row = bm + wr * 64 + fm * 16 + (lane >> 4) * 4 + r;
        int col = bn + wc * 64 + fn * 16 + (lane & 15);
        if (row < M) {
          if constexpr (BF16OUT) {
            Cc[(size_t)row * N + col] = bfhi(acc[fm][fn][r]);
          } else {
            C[(size_t)row * N + col] = acc[fm][fn][r];
          }
        }
      }
    }
  }
}

// ---------------- attention dots: one wave per node, coalesced full-row read ----------------
// BF16IN: h rows are bf16; else fp32.
template <int C, bool BF16IN>
__global__ __launch_bounds__(256) void adot_kernel(const void* __restrict__ h_,
                                                   const float* __restrict__ att_src,
                                                   const float* __restrict__ att_dst,
                                                   float* __restrict__ a_src,
                                                   float* __restrict__ a_dst, int N) {
  int w = (blockIdx.x * 256 + threadIdx.x) >> 6;
  int lane = threadIdx.x & 63;
  if (w >= N) return;
  int head = lane >> 4;
  int l16 = lane & 15;
  float s, d;
  if constexpr (C == 32) {
    float h0, h1v;
    if constexpr (BF16IN) {
      u16x2 hv = *(const u16x2*)&((const u16*)h_)[(size_t)w * 128 + lane * 2];
      h0 = bf2f(hv.x); h1v = bf2f(hv.y);
    } else {
      float2 hv = *(const float2*)&((const float*)h_)[(size_t)w * 128 + lane * 2];
      h0 = hv.x; h1v = hv.y;
    }
    float2 sv = *(const float2*)&att_src[head * 32 + l16 * 2];
    float2 dv = *(const float2*)&att_dst[head * 32 + l16 * 2];
    s = h0 * sv.x + h1v * sv.y;
    d = h0 * dv.x + h1v * dv.y;
  } else {
    float h0, h1v, h2v, h3v;
    if constexpr (BF16IN) {
      u16x4 hv = *(const u16x4*)&((const u16*)h_)[(size_t)w * 256 + lane * 4];
      h0 = bf2f(hv.x); h1v = bf2f(hv.y); h2v = bf2f(hv.z); h3v = bf2f(hv.w);
    } else {
      float4 hv = *(const float4*)&((const float*)h_)[(size_t)w * 256 + lane * 4];
      h0 = hv.x; h1v = hv.y; h2v = hv.z; h3v = hv.w;
    }
    float4 sv = *(const float4*)&att_src[head * 64 + l16 * 4];
    float4 dv = *(const float4*)&att_dst[head * 64 + l16 * 4];
    s = h0 * sv.x + h1v * sv.y + h2v * sv.z + h3v * sv.w;
    d = h0 * dv.x + h1v * dv.y + h2v * dv.z + h3v * dv.w;
  }
#pragma unroll
  for (int o = 1; o < 16; o <<= 1) {
    s += __shfl_xor(s, o);
    d += __shfl_xor(d, o);
  }
  if (l16 == 0) {
    a_src[(size_t)w * 4 + head] = s;
    a_dst[(size_t)w * 4 + head] = d;
  }
}

// ---------------- layer-1 aggregation: bf16 gather (unroll-4); writes x2 bf16 hi/lo ----------------
__global__ __launch_bounds__(256) void agg1_kernel(
    const u16* __restrict__ h1c, const float* __restrict__ asrc, const float* __restrict__ adst,
    const int* __restrict__ off, const int* __restrict__ es,
    const float* __restrict__ b1, u16* __restrict__ x2h, u16* __restrict__ x2l, int N) {
  int n = (blockIdx.x * 256 + threadIdx.x) >> 6;
  int lane = threadIdx.x & 63;
  if (n >= N) return;
  int beg = off[n], end = off[n + 1];
  int myh = lane >> 4;
  float admy = adst[(size_t)n * 4 + myh];
  float sum = 0.f;
  float2 acc = make_float2(0.f, 0.f);
  int j = beg;
  for (; j + 3 < end; j += 4) {
    int se0 = es[j], se1 = es[j + 1], se2 = es[j + 2], se3 = es[j + 3];
    u16x2 r0 = *(const u16x2*)&h1c[(size_t)se0 * 128 + lane * 2];
    u16x2 r1 = *(const u16x2*)&h1c[(size_t)se1 * 128 + lane * 2];
    u16x2 r2 = *(const u16x2*)&h1c[(size_t)se2 * 128 + lane * 2];
    u16x2 r3 = *(const u16x2*)&h1c[(size_t)se3 * 128 + lane * 2];
    float w0 = __expf(leaky(asrc[(size_t)se0 * 4 + myh] + admy));
    float w1 = __expf(leaky(asrc[(size_t)se1 * 4 + myh] + admy));
    float w2 = __expf(leaky(asrc[(size_t)se2 * 4 + myh] + admy));
    float w3 = __expf(leaky(asrc[(size_t)se3 * 4 + myh] + admy));
    sum += w0; acc.x += w0 * bf2f(r0.x); acc.y += w0 * bf2f(r0.y);
    sum += w1; acc.x += w1 * bf2f(r1.x); acc.y += w1 * bf2f(r1.y);
    sum += w2; acc.x += w2 * bf2f(r2.x); acc.y += w2 * bf2f(r2.y);
    sum += w3; acc.x += w3 * bf2f(r3.x); acc.y += w3 * bf2f(r3.y);
  }
  for (; j < end; ++j) {
    int se = es[j];
    float w = __expf(leaky(asrc[(size_t)se * 4 + myh] + admy));
    sum += w;
    u16x2 hv = *(const u16x2*)&h1c[(size_t)se * 128 + lane * 2];
    acc.x += w * bf2f(hv.x);
    acc.y += w * bf2f(hv.y);
  }
  float rs = 1.f / sum;
  int c = lane * 2;
  float2 bv = *(const float2*)&b1[c];
  float y0 = acc.x * rs + bv.x;
  float y1 = acc.y * rs + bv.y;
  y0 = y0 > 0.f ? y0 : expm1f(y0);  // ELU
  y1 = y1 > 0.f ? y1 : expm1f(y1);
  u16 h0, l0, h1b, l1b;
  bfsplit(y0, h0, l0);
  bfsplit(y1, h1b, l1b);
  u16x2 hw = {h0, h1b};
  u16x2 lw = {l0, l1b};
  *(u16x2*)&x2h[(size_t)n * 128 + c] = hw;
  *(u16x2*)&x2l[(size_t)n * 128 + c] = lw;
}

// ---------------- layer-2 aggregation: bf16 gather (unroll-4) + fused head-mean + bias ----------------
__global__ __launch_bounds__(256) void agg2_kernel(
    const u16* __restrict__ h2c, const float* __restrict__ asrc, const float* __restrict__ adst,
    const int* __restrict__ off, const int* __restrict__ es,
    const float* __restrict__ b2, float* __restrict__ out, int N) {
  int n = (blockIdx.x * 256 + threadIdx.x) >> 6;
  int lane = threadIdx.x & 63;
  if (n >= N) return;
  int beg = off[n], end = off[n + 1];
  int myh = lane >> 4;
  float admy = adst[(size_t)n * 4 + myh];
  float sum = 0.f;
  float4 acc = make_float4(0.f, 0.f, 0.f, 0.f);
  int j = beg;
  for (; j + 3 < end; j += 4) {
    int se0 = es[j], se1 = es[j + 1], se2 = es[j + 2], se3 = es[j + 3];
    u16x4 r0 = *(const u16x4*)&h2c[(size_t)se0 * 256 + lane * 4];
    u16x4 r1 = *(const u16x4*)&h2c[(size_t)se1 * 256 + lane * 4];
    u16x4 r2 = *(const u16x4*)&h2c[(size_t)se2 * 256 + lane * 4];
    u16x4 r3 = *(const u16x4*)&h2c[(size_t)se3 * 256 + lane * 4];
    float w0 = __expf(leaky(asrc[(size_t)se0 * 4 + myh] + admy));
    float w1 = __expf(leaky(asrc[(size_t)se1 * 4 + myh] + admy));
    float w2 = __expf(leaky(asrc[(size_t)se2 * 4 + myh] + admy));
    float w3 = __expf(leaky(asrc[(size_t)se3 * 4 + myh] + admy));
    sum += w0;
    acc.x += w0 * bf2f(r0.x); acc.y += w0 * bf2f(r0.y);
    acc.z += w0 * bf2f(r0.z); acc.w += w0 * bf2f(r0.w);
    sum += w1;
    acc.x += w1 * bf2f(r1.x); acc.y += w1 * bf2f(r1.y);
    acc.z += w1 * bf2f(r1.z); acc.w += w1 * bf2f(r1.w);
    sum += w2;
    acc.x += w2 * bf2f(r2.x); acc.y += w2 * bf2f(r2.y);
    acc.z += w2 * bf2f(r2.z); acc.w += w2 * bf2f(r2.w);
    sum += w3;
    acc.x += w3 * bf2f(r3.x); acc.y += w3 * bf2f(r3.y);
    acc.z += w3 * bf2f(r3.z); acc.w += w3 * bf2f(r3.w);
  }
  for (; j < end; ++j) {
    int se = es[j];
    float w = __expf(leaky(asrc[(size_t)se * 4 + myh] + admy));
    sum += w;
    u16x4 hv = *(const u16x4*)&h2c[(size_t)se * 256 + lane * 4];
    acc.x += w * bf2f(hv.x);
    acc.y += w * bf2f(hv.y);
    acc.z += w * bf2f(hv.z);
    acc.w += w * bf2f(hv.w);
  }
  float rs = 1.f / sum;
  acc.x *= rs; acc.y *= rs; acc.z *= rs; acc.w *= rs;
#pragma unroll
  for (int d = 16; d < 64; d <<= 1) {
    acc.x += __shfl_xor(acc.x, d);
    acc.y += __shfl_xor(acc.y, d);
    acc.z += __shfl_xor(acc.z, d);
    acc.w += __shfl_xor(acc.w, d);
  }
  if (lane < 16) {
    int c = lane * 4;
    float4 bv = *(const float4*)&b2[c];
    float4 o;
    o.x = acc.x * 0.25f + bv.x;
    o.y = acc.y * 0.25f + bv.y;
    o.z = acc.z * 0.25f + bv.z;
    o.w = acc.w * 0.25f + bv.w;
    *(float4*)&out[(size_t)n * 64 + c] = o;
  }
}

static inline int ceil_div(int a, int b) { return (a + b - 1) / b; }

extern "C" void kernel_launch(void* const* d_in, const int* in_sizes, int n_in,
                              void* d_out, int out_size, void* d_ws, size_t ws_size,
                              hipStream_t stream) {
  const float* x = (const float*)d_in[0];
  const int* src = (const int*)d_in[1];
  const int* dst = (const int*)d_in[2];
  const float* W1 = (const float*)d_in[3];
  const float* att_src1 = (const float*)d_in[4];
  const float* att_dst1 = (const float*)d_in[5];
  const float* b1 = (const float*)d_in[6];
  const float* W2 = (const float*)d_in[7];
  const float* att_src2 = (const float*)d_in[8];
  const float* att_dst2 = (const float*)d_in[9];
  const float* b2 = (const float*)d_in[10];
  float* out = (float*)d_out;

  const int N = in_sizes[0] / 512;        // 100000 nodes
  const int E = in_sizes[1];              // 1700000 edges
  const int MP = ceil_div(N, 128) * 128;  // padded rows for 128-tall tiles

  // -------- workspace layout (R8-proven) --------
  char* ws = (char*)d_ws;
  size_t o = 0;
  auto alloc = [&](size_t bytes) -> void* {
    o = (o + 255) & ~(size_t)255;
    void* p = ws + o;
    o += bytes;
    return p;
  };
  // region A: h2c bf16 (N*256), written by gemm2 epilogue, read by adot2 + agg2.
  u16* h2c = (u16*)alloc((size_t)N * 256 * 2);
  // region B: h1c bf16 (N*128), written by gemm1 epilogue, read by adot1 + agg1.
  u16* h1c = (u16*)alloc((size_t)N * 128 * 2);
  // region C: x2h + x2l (MP*128 bf16 each). CSR temporaries alias x2h head
  // (dead before agg1 writes x2h).
  u16* x2h = (u16*)alloc((size_t)MP * 128 * 2);
  u16* x2l = (u16*)alloc((size_t)MP * 128 * 2);
  int* deg = (int*)x2h;
  int* exc = deg + N;
  int* cur = exc + N;
  int* bsum = cur + N;      // 256 ints
  int* bbase = bsum + 256;  // 256 ints
  // persistent buffers
  float* as1 = (float*)alloc((size_t)N * 4 * 4);
  float* ad1 = (float*)alloc((size_t)N * 4 * 4);
  float* as2 = (float*)alloc((size_t)N * 4 * 4);
  float* ad2 = (float*)alloc((size_t)N * 4 * 4);
  int* off = (int*)alloc((size_t)(N + 1) * 4);
  int* es = (int*)alloc((size_t)E * 4);
  // fragment-order bf16 hi/lo weight panels
  u16* Bh1 = (u16*)alloc((size_t)512 * 128 * 2);
  u16* Bl1 = (u16*)alloc((size_t)512 * 128 * 2);
  u16* Bh2 = (u16*)alloc((size_t)128 * 256 * 2);
  u16* Bl2 = (u16*)alloc((size_t)128 * 256 * 2);

  const int nb = ceil_div(N, 512);  // 196 (<=256 -> single scan2 block)

  // -------- weight conversion (tiny) --------
  wconv_kernel<<<(512 / 32) * (128 / 16), 64, 0, stream>>>(W1, Bh1, Bl1, 512, 128);
  wconv_kernel<<<(128 / 32) * (256 / 16), 64, 0, stream>>>(W2, Bh2, Bl2, 128, 256);

  // -------- zero x2 padding rows (rows N..MP-1 read unguarded by gemm2's A-load) --------
  hipMemsetAsync(x2h + (size_t)N * 128, 0, (size_t)(MP - N) * 128 * 2, stream);
  hipMemsetAsync(x2l + (size_t)N * 128, 0, (size_t)(MP - N) * 128 * 2, stream);

  // -------- CSR build (shared by both layers) --------
  hipMemsetAsync(deg, 0, (size_t)N * 4, stream);
  hist_kernel<<<ceil_div(E, 256), 256, 0, stream>>>(dst, deg, E);
  scan1_kernel<<<nb, 512, 0, stream>>>(deg, exc, bsum, N);
  scan2_kernel<<<1, 256, 0, stream>>>(bsum, bbase, nb);
  scan3_kernel<<<ceil_div(N, 256), 256, 0, stream>>>(exc, bbase, off, cur, N, E);
  scatter_kernel<<<ceil_div(E, 256), 256, 0, stream>>>(src, dst, cur, es, E);

  // -------- layer 1 (h1 stored bf16-only) --------
  gemm_mfma<true, true, 512><<<dim3(MP / 128, 1), 256, 0, stream>>>(
      x, nullptr, nullptr, Bh1, Bl1, nullptr, h1c, N, 128);
  adot_kernel<32, true><<<ceil_div(N * 64, 256), 256, 0, stream>>>(
      h1c, att_src1, att_dst1, as1, ad1, N);
  agg1_kernel<<<ceil_div(N, 4), 256, 0, stream>>>(h1c, as1, ad1, off, es, b1, x2h, x2l, N);

  // -------- layer 2 (h2 stored bf16-only, dedicated region) --------
  gemm_mfma<false, true, 128><<<dim3(MP / 128, 2), 256, 0, stream>>>(
      nullptr, x2h, x2l, Bh2, Bl2, nullptr, h2c, N, 256);
  adot_kernel<64, true><<<ceil_div(N * 64, 256), 256, 0, stream>>>(
      h2c, att_src2, att_dst2, as2, ad2, N);
  agg2_kernel<<<ceil_div(N, 4), 256, 0, stream>>>(h2c, as2, ad2, off, es, b2, out, N);
}